// Round 1
// baseline (308.902 us; speedup 1.0000x reference)
//
#include <hip/hip_runtime.h>
#include <math.h>

#define B_ 4
#define S_ 2048
#define E_ 1024
#define H_ 16
#define D_ 64

using f32x4 = __attribute__((ext_vector_type(4))) float;
using s16x8 = __attribute__((ext_vector_type(8))) short;

// fp32 -> bf16 bits, round-to-nearest-even
__device__ __forceinline__ unsigned short f2bf(float f) {
    unsigned int u = __float_as_uint(f);
    u = (u + 0x7FFFu + ((u >> 16) & 1u)) >> 16;
    return (unsigned short)u;
}

// pack hi16(a)|hi16(b)<<16 with +0x8000 rounding (round-half-up, 3 VALU ops)
__device__ __forceinline__ unsigned int pack_bf2(float lo, float hi) {
    const unsigned int ulo = __float_as_uint(lo) + 0x8000u;
    const unsigned int uhi = __float_as_uint(hi) + 0x8000u;
    return __builtin_amdgcn_perm(uhi, ulo, 0x07060302u);
}

// async global->LDS DMA, 16B per lane; LDS dest = wave-uniform base + lane*16
__device__ __forceinline__ void load_lds16(const void* g, void* l) {
    __builtin_amdgcn_global_load_lds(
        (const __attribute__((address_space(1))) void*)g,
        (__attribute__((address_space(3))) void*)l, 16, 0, 0);
}

#define WAITV(n) asm volatile("s_waitcnt vmcnt(" #n ")" ::: "memory")

// Q pre-scale: 1/sqrt(D) * log2(e) -> softmax in base-2 (native v_exp_f32)
#define QSCALE 0.18033688011112042f

// ---------------------------------------------------------------------------
// x (fp32 [8192][1024]) -> bf16, same layout.
// ---------------------------------------------------------------------------
__global__ __launch_bounds__(256)
void cast_x(const float* __restrict__ in, unsigned short* __restrict__ out)
{
    const size_t idx = (size_t)blockIdx.x * 2048 + threadIdx.x * 8;
    const float4 v0 = *(const float4*)&in[idx];
    const float4 v1 = *(const float4*)&in[idx + 4];
    uint4 p;
    p.x = (unsigned)f2bf(v0.x) | ((unsigned)f2bf(v0.y) << 16);
    p.y = (unsigned)f2bf(v0.z) | ((unsigned)f2bf(v0.w) << 16);
    p.z = (unsigned)f2bf(v1.x) | ((unsigned)f2bf(v1.y) << 16);
    p.w = (unsigned)f2bf(v1.z) | ((unsigned)f2bf(v1.w) << 16);
    *(uint4*)&out[idx] = p;
}

// ---------------------------------------------------------------------------
// Weight transpose + bf16 cast (unchanged).
// ---------------------------------------------------------------------------
__global__ __launch_bounds__(256)
void transpose_w(const float* __restrict__ wq, const float* __restrict__ wk,
                 const float* __restrict__ wv, const float* __restrict__ wo,
                 unsigned short* __restrict__ Wqkvt, unsigned short* __restrict__ Wot)
{
    __shared__ float T[64][68];
    const int z = blockIdx.z;
    const float* in;
    unsigned short* out;
    int inStride, r0, c0;
    if (z < 48) {
        if (blockIdx.y != 0) return;
        const int t = z >> 4, h = z & 15;
        const float* W = (t == 0) ? wq : ((t == 1) ? wk : wv);
        in = W + (size_t)h * (E_ * D_);
        inStride = 64;
        out = Wqkvt + (size_t)(t * 1024 + h * 64) * 1024;
        r0 = blockIdx.x * 64; c0 = 0;
    } else {
        in = wo; inStride = 1024;
        out = Wot;
        r0 = blockIdx.x * 64; c0 = blockIdx.y * 64;
    }
    const int tid = threadIdx.x;
    #pragma unroll
    for (int i = 0; i < 4; ++i) {
        const int e = tid + i * 256;
        const int row = e >> 4, c4 = e & 15;
        const float4 v = *(const float4*)&in[(size_t)(r0 + row) * inStride + c0 + c4 * 4];
        T[row][c4 * 4 + 0] = v.x; T[row][c4 * 4 + 1] = v.y;
        T[row][c4 * 4 + 2] = v.z; T[row][c4 * 4 + 3] = v.w;
    }
    __syncthreads();
    #pragma unroll
    for (int i = 0; i < 2; ++i) {
        const int e = tid + i * 256;
        const int c = e >> 3, ch = e & 7;
        unsigned short h8[8];
        #pragma unroll
        for (int j = 0; j < 8; ++j) h8[j] = f2bf(T[ch * 8 + j][c]);
        uint4 p;
        p.x = (unsigned)h8[0] | ((unsigned)h8[1] << 16);
        p.y = (unsigned)h8[2] | ((unsigned)h8[3] << 16);
        p.z = (unsigned)h8[4] | ((unsigned)h8[5] << 16);
        p.w = (unsigned)h8[6] | ((unsigned)h8[7] << 16);
        *(uint4*)&out[(size_t)(c0 + c) * 1024 + r0 + ch * 8] = p;
    }
}

// ---------------------------------------------------------------------------
// bf16 MFMA GEMM v4 — counted-vmcnt ring pipeline (T3-lite + T4 + T5).
//   * BK=32 K-tiles, 4-buffer LDS ring, lookahead 3 tiles.
//   * raw s_barrier (no implicit vmcnt(0) drain) + inline-asm
//     s_waitcnt vmcnt(2*LT) in steady state -> loads stay in flight across
//     barriers; tile t's DMA was issued 3 iterations (~1000 cyc) earlier.
//   * WAR-safe by ring distance: stage(t+3) reuses the buffer whose last
//     reader finished before the barrier at the top of iteration t.
//   * XOR source-pre-swizzle (4 chunks/row) -> conflict-free ds_read_b128,
//     same scheme as the proven 64-col version.
//   * 8 waves (2M x 4N), 512 threads, 1 block/CU.
// MODE 0: QKV  — BM=256, BN=192, grid 32x16 = 512 blocks (2 exact CU rounds).
//               Q/K to [bh][s][d]; V transposed to Vt [bh][d][s].
// MODE 1: out  — BM=128, BN=256, grid 64x4 = 256 blocks (1 exact CU round).
// ---------------------------------------------------------------------------
template<int MODE>
__global__ __launch_bounds__(512, 2)
void gemm_mfma(const unsigned short* __restrict__ A,
               const unsigned short* __restrict__ Bt,
               const float* __restrict__ bq, const float* __restrict__ bk,
               const float* __restrict__ bv, const float* __restrict__ bo,
               unsigned short* __restrict__ Qb, unsigned short* __restrict__ Kb,
               unsigned short* __restrict__ Vt, float* __restrict__ Cout)
{
    constexpr int BM  = (MODE == 0) ? 256 : 128;
    constexpr int BN  = (MODE == 0) ? 192 : 256;
    constexpr int MTF = BM / 32;            // per-wave 16-row m-frags (8 / 4)
    constexpr int NTF = BN / 64;            // per-wave 16-col n-frags (3 / 4)
    constexpr int RBA = BM / 16;            // A 16-row staging blocks
    constexpr int RBB = BN / 16;            // B 16-row staging blocks
    constexpr int NU  = RBA + RBB;          // staging units per K-tile (28 / 24)

    __shared__ short As[4][BM * 32];
    __shared__ short Bs[4][BN * 32];

    const int tid  = threadIdx.x;
    const int w    = tid >> 6, lane = tid & 63;
    const int g    = lane >> 4, l15 = lane & 15;
    const int wm   = w >> 2, wn = w & 3;
    const int mbase = blockIdx.x * BM;
    const int nbase = blockIdx.y * BN;

    // staging source pre-swizzle: LDS chunk c of row r holds global chunk
    // c ^ (r & 3)  (rows are 32 shorts = 4 chunks of 8)
    const int srow4  = lane >> 2;           // 0..15 (row within 16-row block)
    const int schunk = (lane & 3) ^ (srow4 & 3);
    const size_t aoff = (size_t)(mbase + srow4) * 1024 + schunk * 8;
    const size_t boff = (size_t)(nbase + srow4) * 1024 + schunk * 8;

    f32x4 acc[MTF][NTF];
    #pragma unroll
    for (int mt = 0; mt < MTF; ++mt)
        #pragma unroll
        for (int nt = 0; nt < NTF; ++nt)
            acc[mt][nt] = (f32x4){0.f, 0.f, 0.f, 0.f};

    // stage one K-tile (unit u -> wave u%8, flattened A-blocks then B-blocks)
    auto STAGE = [&](int t, int buf) {
        const int k0 = t * 32;
        #pragma unroll
        for (int i = 0; i < (NU + 7) / 8; ++i) {
            const int u = w + i * 8;
            if (NU % 8 != 0 && u >= NU) continue;
            if (u < RBA) {
                load_lds16(&A[aoff + (size_t)(u * 16) * 1024 + k0],
                           &As[buf][u * 512]);
            } else {
                const int v = u - RBA;
                load_lds16(&Bt[boff + (size_t)(v * 16) * 1024 + k0],
                           &Bs[buf][v * 512]);
            }
        }
    };

    // prologue: fill 3 tiles of the ring
    STAGE(0, 0); STAGE(1, 1); STAGE(2, 2);

    const int qa = (g ^ (l15 & 3)) * 8;     // swizzled k-chunk for reads

    #pragma unroll 1
    for (int t = 0; t < 32; ++t) {
        // wait for tile t (own loads); keep later tiles' loads in flight.
        // per-wave loads/tile LT: MODE0 -> 4 (w<4) or 3 (w>=4); MODE1 -> 3.
        if (t < 30) {
            if constexpr (MODE == 0) { if (w < 4) WAITV(8); else WAITV(6); }
            else                     WAITV(6);
        } else if (t == 30) {
            if constexpr (MODE == 0) { if (w < 4) WAITV(4); else WAITV(3); }
            else                     WAITV(3);
        } else {
            WAITV(0);
        }
        __builtin_amdgcn_s_barrier();       // raw: no compiler vmcnt(0) drain

        if (t < 29) STAGE(t + 3, (t + 3) & 3);

        const int buf = t & 3;
        s16x8 af[MTF], bf[NTF];
        #pragma unroll
        for (int mt = 0; mt < MTF; ++mt)
            af[mt] = *(const s16x8*)&As[buf][(wm * (BM / 2) + mt * 16 + l15) * 32 + qa];
        #pragma unroll
        for (int nt = 0; nt < NTF; ++nt)
            bf[nt] = *(const s16x8*)&Bs[buf][(wn * (BN / 4) + nt * 16 + l15) * 32 + qa];

        __builtin_amdgcn_s_setprio(1);
        #pragma unroll
        for (int mt = 0; mt < MTF; ++mt)
            #pragma unroll
            for (int nt = 0; nt < NTF; ++nt)
                acc[mt][nt] = __builtin_amdgcn_mfma_f32_16x16x32_bf16(
                    af[mt], bf[nt], acc[mt][nt], 0, 0, 0);
        __builtin_amdgcn_s_setprio(0);
    }

    #pragma unroll
    for (int nt = 0; nt < NTF; ++nt) {
        const int ncol = nbase + wn * (BN / 4) + nt * 16 + l15;
        if (MODE == 0) {
            const int t  = ncol >> 10;
            const int hh = (ncol >> 6) & 15;
            const int d  = ncol & 63;
            const float* bias = (t == 0) ? bq : ((t == 1) ? bk : bv);
            const float sc = (t == 0) ? QSCALE : 1.0f;
            const float bval = bias[hh * 64 + d];
            #pragma unroll
            for (int mt = 0; mt < MTF; ++mt)
                #pragma unroll
                for (int r = 0; r < 4; ++r) {
                    const int m = mbase + wm * (BM / 2) + mt * 16 + g * 4 + r;
                    const int b = m >> 11, s = m & 2047;
                    const unsigned short val = f2bf((acc[mt][nt][r] + bval) * sc);
                    if (t == 2)
                        Vt[((size_t)(b * 16 + hh) * 64 + d) * 2048 + s] = val;
                    else {
                        unsigned short* Out = (t == 0) ? Qb : Kb;
                        Out[((size_t)(b * 16 + hh) * 2048 + s) * 64 + d] = val;
                    }
                }
        } else {
            const float bval = bo[ncol];
            #pragma unroll
            for (int mt = 0; mt < MTF; ++mt)
                #pragma unroll
                for (int r = 0; r < 4; ++r) {
                    const int m = mbase + wm * (BM / 2) + mt * 16 + g * 4 + r;
                    Cout[(size_t)m * 1024 + ncol] = acc[mt][nt][r] + bval;
                }
        }
    }
}

// ---------------------------------------------------------------------------
// MFMA flash attention v7 (unchanged) — S^T formulation, P in LDS
// [query][key] (b64 writes / b128 reads), no online max, deferred l,
// causal pairing, K/V LDS double-buffer + register prefetch, spill-free.
// ---------------------------------------------------------------------------
#define LDK 72
__global__ __launch_bounds__(512, 2)
void attn_mfma(const unsigned short* __restrict__ Qb,
               const unsigned short* __restrict__ Kb,
               const unsigned short* __restrict__ Vt,
               unsigned short* __restrict__ O)
{
    __shared__ short Kls[2][64 * LDK];
    __shared__ short Vls[2][64 * LDK];       // [d][key]
    __shared__ short Pls[8][16 * LDK];       // per-wave P [query][key]

    const int tid  = threadIdx.x;
    const int w    = tid >> 6;               // 0..7
    const int lane = tid & 63;
    const int g    = lane >> 4;
    const int l15  = lane & 15;
    const int j    = blockIdx.x;             // 0..7 (light tile index)
    const int j2   = 15 - j;                 // heavy tile index
    const int h    = blockIdx.y;
    const int b    = blockIdx.z;

    const size_t hb = (size_t)(b * 16 + h) * (2048 * 64);
    const int qH = j2 * 128 + w * 16;        // this wave's heavy query base
    const int qL = j * 128 + w * 16;         // this wave's light query base

    s16x8 aqH[2], aqL[2];
    {
        const int rh = qH + l15, rl = qL + l15;
        aqH[0] = *(const s16x8*)&Qb[hb + (size_t)rh * 64 + g * 8];
        aqH[1] = *(const s16x8*)&Qb[hb + (size_t)rh * 64 + 32 + g * 8];
        aqL[0] = *(const s16x8*)&Qb[hb + (size_t)rl * 64 + g * 8];
        aqL[1] = *(const s16x8*)&Qb[hb + (size_t)rl * 64 + 32 + g * 8];
    }

    float lsumH = 0.f, lsumL = 0.f;
    f32x4 OH[4], OL[4];                      // O^T: row d = nt*16+l15, col query
    #pragma unroll
    for (int nt = 0; nt < 4; ++nt) { OH[nt] = (f32x4){0.f,0.f,0.f,0.f}; OL[nt] = (f32x4){0.f,0.f,0.f,0.f}; }

    const int stages      = 32 - 2 * j;
    const int lightStages = 2 * j + 2;

    const int srow = tid >> 3, spart = tid & 7;
    uint4 kreg = *(const uint4*)&Kb[hb + (size_t)srow * 64 + spart * 8];
    uint4 vreg = *(const uint4*)&Vt[hb + (size_t)srow * 2048 + spart * 8];

    for (int t = 0; t < stages; ++t) {
        const int t0  = t * 64;
        const int buf = t & 1;
        *(uint4*)&Kls[buf][srow * LDK + spart * 8] = kreg;
        *(uint4*)&Vls[buf][srow * LDK + spart * 8] = vreg;
        if (t + 1 < stages) {
            kreg = *(const uint4*)&Kb[hb + (size_t)(t0 + 64 + srow) * 64 + spart * 8];
            vreg = *(const uint4*)&Vt[hb + (size_t)srow * 2048 + t0 + 64 + spart * 8];
        }
        __syncthreads();

        #pragma unroll
        for (int half = 0; half < 2; ++half) {
            if (half == 1 && t >= lightStages) break;
            const s16x8* aq   = (half == 0) ? aqH : aqL;
            const int qbase   = (half == 0) ? qH : qL;
            f32x4* Oacc       = (half == 0) ? OH : OL;

            // ---- S^T = K * Q^T : Sf[ct][r] = S[query=l15][key=t0+ct*16+g*4+r]
            f32x4 Sf[4];
            #pragma unroll
            for (int ct = 0; ct < 4; ++ct) {
                f32x4 acc = (f32x4){0.f, 0.f, 0.f, 0.f};
                const s16x8 bk0 = *(const s16x8*)&Kls[buf][(ct * 16 + l15) * LDK + g * 8];
                const s16x8 bk1 = *(const s16x8*)&Kls[buf][(ct * 16 + l15) * LDK + 32 + g * 8];
                acc = __builtin_amdgcn_mfma_f32_16x16x32_bf16(bk0, aq[0], acc, 0, 0, 0);
                acc = __builtin_amdgcn_mfma_f32_16x16x32_bf16(bk1, aq[1], acc, 0, 0, 0);
                Sf[ct] = acc;
            }

            // ---- causal mask (diagonal tiles only) ----
            if (t0 + 63 > qbase) {
                const int query = qbase + l15;
                #pragma unroll
                for (int ct = 0; ct < 4; ++ct) {
                    const int kbase = t0 + ct * 16 + g * 4;
                    #pragma unroll
                    for (int r = 0; r < 4; ++r)
                        if (kbase + r > query) Sf[ct][r] = -1e30f;
                }
            }

            // ---- p = exp2(s); partial row-sum ----
            float lacc = 0.f;
            #pragma unroll
            for (int ct = 0; ct < 4; ++ct) {
                #pragma unroll
                for (int r = 0; r < 4; ++r) Sf[ct][r] = exp2f(Sf[ct][r]);
                lacc += (Sf[ct][0] + Sf[ct][1]) + (Sf[ct][2] + Sf[ct][3]);
            }
            if (half == 0) lsumH += lacc; else lsumL += lacc;

            // ---- write P[query][key]: 4 consecutive keys per lane -> b64 ----
            #pragma unroll
            for (int ct = 0; ct < 4; ++ct) {
                uint2 pw;
                pw.x = pack_bf2(Sf[ct][0], Sf[ct][1]);
                pw.y = pack_bf2(Sf[ct][2], Sf[ct][3]);
                *(uint2*)&Pls[w][l15 * LDK + ct * 16 + g * 4] = pw;
            }

            // ---- PV: O^T += V^T * P^T (B-frag = b128 read of P row) ----
            const s16x8 pf0 = *(const s16x8*)&Pls[w][l15 * LDK + g * 8];
            const s16x8 pf1 = *(const s16x8*)&Pls[w][l15 * LDK + 32 + g * 8];
            #pragma unroll
            for (int nt = 0; nt < 4; ++nt) {
                const s16x8 bv0 = *(const s16x8*)&Vls[buf][(nt * 16 + l15) * LDK + g * 8];
                const s16x8 bv1 = *(const s16x8*)&Vls[buf][(nt * 16 + l15) * LDK + 32 + g * 8];
                Oacc[nt] = __builtin_amdgcn_mfma_f32_16x16x32_bf16(bv0, pf0, Oacc[nt], 0, 0, 0);
                Oacc[nt] = __builtin_amdgcn_mfma_f32_16x16x32_bf16(bv1, pf1, Oacc[nt], 0, 0, 0);
            }
        }
    }

    // ---- epilogue: finish l reduction (across the 4 quads), store O ----
    lsumH += __shfl_xor(lsumH, 16);
    lsumH += __shfl_xor(lsumH, 32);
    lsumL += __shfl_xor(lsumL, 16);
    lsumL += __shfl_xor(lsumL, 32);
    const float invH = 1.0f / lsumH;
    const float invL = 1.0f / lsumL;

    #pragma unroll
    for (int half = 0; half < 2; ++half) {
        const f32x4* Oacc = (half == 0) ? OH : OL;
        const float  inv  = (half == 0) ? invH : invL;
        const int query   = ((half == 0) ? qH : qL) + l15;
        #pragma unroll
        for (int nt = 0; nt < 4; ++nt) {
            uint2 pk;
            pk.x = pack_bf2(Oacc[nt][0] * inv, Oacc[nt][1] * inv);
            pk.y = pack_bf2(Oacc[nt][2] * inv, Oacc[nt][3] * inv);
            *(uint2*)&O[(size_t)(b * 2048 + query) * 1024 + h * 64 + nt * 16 + g * 4] = pk;
        }
    }
}

// ---------------------------------------------------------------------------
// ws (ushort elems): xb 8M | Wqkvt 3M | Wot 1M | Qb/Kb/Vt 8M each | Ob 8M
// ---------------------------------------------------------------------------
extern "C" void kernel_launch(void* const* d_in, const int* in_sizes, int n_in,
                              void* d_out, int out_size, void* d_ws, size_t ws_size,
                              hipStream_t stream) {
    const float* x  = (const float*)d_in[0];
    const float* wq = (const float*)d_in[1];
    const float* bq = (const float*)d_in[2];
    const float* wk = (const float*)d_in[3];
    const float* bk = (const float*)d_in[4];
    const float* wv = (const float*)d_in[5];
    const float* bv = (const float*)d_in[6];
    const float* wo = (const float*)d_in[7];
    const float* bo = (const float*)d_in[8];
    float* out = (float*)d_out;

    const size_t hsz = (size_t)B_ * H_ * S_ * D_;        // 8388608
    unsigned short* xb    = (unsigned short*)d_ws;
    unsigned short* Wqkvt = xb + hsz;
    unsigned short* Wot   = Wqkvt + (size_t)3072 * 1024;
    unsigned short* Qb    = Wot + (size_t)1024 * 1024;
    unsigned short* Kb    = Qb + hsz;
    unsigned short* Vt    = Kb + hsz;
    unsigned short* Ob    = Vt + hsz;

    cast_x<<<4096, 256, 0, stream>>>(x, xb);
    transpose_w<<<dim3(16, 16, 49), 256, 0, stream>>>(wq, wk, wv, wo, Wqkvt, Wot);
    gemm_mfma<0><<<dim3(32, 16), 512, 0, stream>>>(
        xb, Wqkvt, bq, bk, bv, nullptr, Qb, Kb, Vt, nullptr);
    attn_mfma<<<dim3(8, H_, B_), 512, 0, stream>>>(Qb, Kb, Vt, Ob);
    gemm_mfma<1><<<dim3(64, 4), 512, 0, stream>>>(
        Ob, Wot, nullptr, nullptr, nullptr, bo, nullptr, nullptr, nullptr, out);
}

// Round 2
// 303.045 us; speedup vs baseline: 1.0193x; 1.0193x over previous
//
#include <hip/hip_runtime.h>
#include <math.h>

#define B_ 4
#define S_ 2048
#define E_ 1024
#define H_ 16
#define D_ 64

using f32x4 = __attribute__((ext_vector_type(4))) float;
using s16x8 = __attribute__((ext_vector_type(8))) short;

// fp32 -> bf16 bits, round-to-nearest-even
__device__ __forceinline__ unsigned short f2bf(float f) {
    unsigned int u = __float_as_uint(f);
    u = (u + 0x7FFFu + ((u >> 16) & 1u)) >> 16;
    return (unsigned short)u;
}

// pack hi16(a)|hi16(b)<<16 with +0x8000 rounding (round-half-up, 3 VALU ops)
__device__ __forceinline__ unsigned int pack_bf2(float lo, float hi) {
    const unsigned int ulo = __float_as_uint(lo) + 0x8000u;
    const unsigned int uhi = __float_as_uint(hi) + 0x8000u;
    return __builtin_amdgcn_perm(uhi, ulo, 0x07060302u);
}

// async global->LDS DMA, 16B per lane; LDS dest = wave-uniform base + lane*16
__device__ __forceinline__ void load_lds16(const void* g, void* l) {
    __builtin_amdgcn_global_load_lds(
        (const __attribute__((address_space(1))) void*)g,
        (__attribute__((address_space(3))) void*)l, 16, 0, 0);
}

#define WAITV(n) asm volatile("s_waitcnt vmcnt(" #n ")" ::: "memory")

// Q pre-scale: 1/sqrt(D) * log2(e) -> softmax in base-2 (native v_exp_f32)
#define QSCALE 0.18033688011112042f

// ---------------------------------------------------------------------------
// x (fp32 [8192][1024]) -> bf16, same layout.
// ---------------------------------------------------------------------------
__global__ __launch_bounds__(256)
void cast_x(const float* __restrict__ in, unsigned short* __restrict__ out)
{
    const size_t idx = (size_t)blockIdx.x * 2048 + threadIdx.x * 8;
    const float4 v0 = *(const float4*)&in[idx];
    const float4 v1 = *(const float4*)&in[idx + 4];
    uint4 p;
    p.x = (unsigned)f2bf(v0.x) | ((unsigned)f2bf(v0.y) << 16);
    p.y = (unsigned)f2bf(v0.z) | ((unsigned)f2bf(v0.w) << 16);
    p.z = (unsigned)f2bf(v1.x) | ((unsigned)f2bf(v1.y) << 16);
    p.w = (unsigned)f2bf(v1.z) | ((unsigned)f2bf(v1.w) << 16);
    *(uint4*)&out[idx] = p;
}

// ---------------------------------------------------------------------------
// Weight transpose + bf16 cast (unchanged).
// ---------------------------------------------------------------------------
__global__ __launch_bounds__(256)
void transpose_w(const float* __restrict__ wq, const float* __restrict__ wk,
                 const float* __restrict__ wv, const float* __restrict__ wo,
                 unsigned short* __restrict__ Wqkvt, unsigned short* __restrict__ Wot)
{
    __shared__ float T[64][68];
    const int z = blockIdx.z;
    const float* in;
    unsigned short* out;
    int inStride, r0, c0;
    if (z < 48) {
        if (blockIdx.y != 0) return;
        const int t = z >> 4, h = z & 15;
        const float* W = (t == 0) ? wq : ((t == 1) ? wk : wv);
        in = W + (size_t)h * (E_ * D_);
        inStride = 64;
        out = Wqkvt + (size_t)(t * 1024 + h * 64) * 1024;
        r0 = blockIdx.x * 64; c0 = 0;
    } else {
        in = wo; inStride = 1024;
        out = Wot;
        r0 = blockIdx.x * 64; c0 = blockIdx.y * 64;
    }
    const int tid = threadIdx.x;
    #pragma unroll
    for (int i = 0; i < 4; ++i) {
        const int e = tid + i * 256;
        const int row = e >> 4, c4 = e & 15;
        const float4 v = *(const float4*)&in[(size_t)(r0 + row) * inStride + c0 + c4 * 4];
        T[row][c4 * 4 + 0] = v.x; T[row][c4 * 4 + 1] = v.y;
        T[row][c4 * 4 + 2] = v.z; T[row][c4 * 4 + 3] = v.w;
    }
    __syncthreads();
    #pragma unroll
    for (int i = 0; i < 2; ++i) {
        const int e = tid + i * 256;
        const int c = e >> 3, ch = e & 7;
        unsigned short h8[8];
        #pragma unroll
        for (int j = 0; j < 8; ++j) h8[j] = f2bf(T[ch * 8 + j][c]);
        uint4 p;
        p.x = (unsigned)h8[0] | ((unsigned)h8[1] << 16);
        p.y = (unsigned)h8[2] | ((unsigned)h8[3] << 16);
        p.z = (unsigned)h8[4] | ((unsigned)h8[5] << 16);
        p.w = (unsigned)h8[6] | ((unsigned)h8[7] << 16);
        *(uint4*)&out[(size_t)(c0 + c) * 1024 + r0 + ch * 8] = p;
    }
}

// ---------------------------------------------------------------------------
// bf16 MFMA GEMM v5 — counted-vmcnt ring pipeline, CONFLICT-FREE swizzle.
//   R1 post-mortem: chunk = c ^ (r&3) gave 2-way bank conflicts within each
//   8-lane b128 service group (lanes l15, l15+4 alias).  Fix: f(r)=(r>>1)&3.
//   Then per 8-lane group, (l15&1, g^f(l15)) is a bijection onto 8 values ->
//   bank starts {0,16,4,20,8,24,12,28}: all 32 banks, conflict-free.
//   * BK=32 K-tiles, 4-buffer LDS ring, lookahead 3 tiles, counted vmcnt
//     (never 0 in steady state), raw s_barrier, setprio around MFMA.
// MODE 0: QKV  — BM=256, BN=192, grid 32x16 = 512 blocks (2 exact CU rounds).
// MODE 1: out  — BM=128, BN=256, grid 64x4 = 256 blocks (1 exact CU round).
// ---------------------------------------------------------------------------
template<int MODE>
__global__ __launch_bounds__(512, 2)
void gemm_mfma(const unsigned short* __restrict__ A,
               const unsigned short* __restrict__ Bt,
               const float* __restrict__ bq, const float* __restrict__ bk,
               const float* __restrict__ bv, const float* __restrict__ bo,
               unsigned short* __restrict__ Qb, unsigned short* __restrict__ Kb,
               unsigned short* __restrict__ Vt, float* __restrict__ Cout)
{
    constexpr int BM  = (MODE == 0) ? 256 : 128;
    constexpr int BN  = (MODE == 0) ? 192 : 256;
    constexpr int MTF = BM / 32;            // per-wave 16-row m-frags (8 / 4)
    constexpr int NTF = BN / 64;            // per-wave 16-col n-frags (3 / 4)
    constexpr int RBA = BM / 16;            // A 16-row staging blocks
    constexpr int RBB = BN / 16;            // B 16-row staging blocks
    constexpr int NU  = RBA + RBB;          // staging units per K-tile (28 / 24)

    __shared__ short As[4][BM * 32];
    __shared__ short Bs[4][BN * 32];

    const int tid  = threadIdx.x;
    const int w    = tid >> 6, lane = tid & 63;
    const int g    = lane >> 4, l15 = lane & 15;
    const int wm   = w >> 2, wn = w & 3;
    const int mbase = blockIdx.x * BM;
    const int nbase = blockIdx.y * BN;

    // staging source pre-swizzle: LDS chunk c of row r holds global chunk
    // c ^ ((r>>1) & 3)   (rows are 32 shorts = 4 chunks of 8)
    const int srow4  = lane >> 2;           // 0..15 (row within 16-row block)
    const int schunk = (lane & 3) ^ ((lane >> 3) & 3);
    const size_t aoff = (size_t)(mbase + srow4) * 1024 + schunk * 8;
    const size_t boff = (size_t)(nbase + srow4) * 1024 + schunk * 8;

    f32x4 acc[MTF][NTF];
    #pragma unroll
    for (int mt = 0; mt < MTF; ++mt)
        #pragma unroll
        for (int nt = 0; nt < NTF; ++nt)
            acc[mt][nt] = (f32x4){0.f, 0.f, 0.f, 0.f};

    // stage one K-tile (unit u -> wave u%8, flattened A-blocks then B-blocks)
    auto STAGE = [&](int t, int buf) {
        const int k0 = t * 32;
        #pragma unroll
        for (int i = 0; i < (NU + 7) / 8; ++i) {
            const int u = w + i * 8;
            if (NU % 8 != 0 && u >= NU) continue;
            if (u < RBA) {
                load_lds16(&A[aoff + (size_t)(u * 16) * 1024 + k0],
                           &As[buf][u * 512]);
            } else {
                const int v = u - RBA;
                load_lds16(&Bt[boff + (size_t)(v * 16) * 1024 + k0],
                           &Bs[buf][v * 512]);
            }
        }
    };

    // prologue: fill 3 tiles of the ring
    STAGE(0, 0); STAGE(1, 1); STAGE(2, 2);

    const int qa = (g ^ ((l15 >> 1) & 3)) * 8;   // swizzled k-chunk for reads

    #pragma unroll 1
    for (int t = 0; t < 32; ++t) {
        // wait for tile t (own loads); keep later tiles' loads in flight.
        // per-wave loads/tile LT: MODE0 -> 4 (w<4) or 3 (w>=4); MODE1 -> 3.
        if (t < 30) {
            if constexpr (MODE == 0) { if (w < 4) WAITV(8); else WAITV(6); }
            else                     WAITV(6);
        } else if (t == 30) {
            if constexpr (MODE == 0) { if (w < 4) WAITV(4); else WAITV(3); }
            else                     WAITV(3);
        } else {
            WAITV(0);
        }
        __builtin_amdgcn_s_barrier();       // raw: no compiler vmcnt(0) drain

        if (t < 29) STAGE(t + 3, (t + 3) & 3);

        const int buf = t & 3;
        s16x8 af[MTF], bf[NTF];
        #pragma unroll
        for (int mt = 0; mt < MTF; ++mt)
            af[mt] = *(const s16x8*)&As[buf][(wm * (BM / 2) + mt * 16 + l15) * 32 + qa];
        #pragma unroll
        for (int nt = 0; nt < NTF; ++nt)
            bf[nt] = *(const s16x8*)&Bs[buf][(wn * (BN / 4) + nt * 16 + l15) * 32 + qa];

        __builtin_amdgcn_s_setprio(1);
        #pragma unroll
        for (int mt = 0; mt < MTF; ++mt)
            #pragma unroll
            for (int nt = 0; nt < NTF; ++nt)
                acc[mt][nt] = __builtin_amdgcn_mfma_f32_16x16x32_bf16(
                    af[mt], bf[nt], acc[mt][nt], 0, 0, 0);
        __builtin_amdgcn_s_setprio(0);
    }

    #pragma unroll
    for (int nt = 0; nt < NTF; ++nt) {
        const int ncol = nbase + wn * (BN / 4) + nt * 16 + l15;
        if (MODE == 0) {
            const int t  = ncol >> 10;
            const int hh = (ncol >> 6) & 15;
            const int d  = ncol & 63;
            const float* bias = (t == 0) ? bq : ((t == 1) ? bk : bv);
            const float sc = (t == 0) ? QSCALE : 1.0f;
            const float bval = bias[hh * 64 + d];
            #pragma unroll
            for (int mt = 0; mt < MTF; ++mt)
                #pragma unroll
                for (int r = 0; r < 4; ++r) {
                    const int m = mbase + wm * (BM / 2) + mt * 16 + g * 4 + r;
                    const int b = m >> 11, s = m & 2047;
                    const unsigned short val = f2bf((acc[mt][nt][r] + bval) * sc);
                    if (t == 2)
                        Vt[((size_t)(b * 16 + hh) * 64 + d) * 2048 + s] = val;
                    else {
                        unsigned short* Out = (t == 0) ? Qb : Kb;
                        Out[((size_t)(b * 16 + hh) * 2048 + s) * 64 + d] = val;
                    }
                }
        } else {
            const float bval = bo[ncol];
            #pragma unroll
            for (int mt = 0; mt < MTF; ++mt)
                #pragma unroll
                for (int r = 0; r < 4; ++r) {
                    const int m = mbase + wm * (BM / 2) + mt * 16 + g * 4 + r;
                    Cout[(size_t)m * 1024 + ncol] = acc[mt][nt][r] + bval;
                }
        }
    }
}

// ---------------------------------------------------------------------------
// MFMA flash attention v7 (unchanged) — S^T formulation, P in LDS
// [query][key] (b64 writes / b128 reads), no online max, deferred l,
// causal pairing, K/V LDS double-buffer + register prefetch, spill-free.
// ---------------------------------------------------------------------------
#define LDK 72
__global__ __launch_bounds__(512, 2)
void attn_mfma(const unsigned short* __restrict__ Qb,
               const unsigned short* __restrict__ Kb,
               const unsigned short* __restrict__ Vt,
               unsigned short* __restrict__ O)
{
    __shared__ short Kls[2][64 * LDK];
    __shared__ short Vls[2][64 * LDK];       // [d][key]
    __shared__ short Pls[8][16 * LDK];       // per-wave P [query][key]

    const int tid  = threadIdx.x;
    const int w    = tid >> 6;               // 0..7
    const int lane = tid & 63;
    const int g    = lane >> 4;
    const int l15  = lane & 15;
    const int j    = blockIdx.x;             // 0..7 (light tile index)
    const int j2   = 15 - j;                 // heavy tile index
    const int h    = blockIdx.y;
    const int b    = blockIdx.z;

    const size_t hb = (size_t)(b * 16 + h) * (2048 * 64);
    const int qH = j2 * 128 + w * 16;        // this wave's heavy query base
    const int qL = j * 128 + w * 16;         // this wave's light query base

    s16x8 aqH[2], aqL[2];
    {
        const int rh = qH + l15, rl = qL + l15;
        aqH[0] = *(const s16x8*)&Qb[hb + (size_t)rh * 64 + g * 8];
        aqH[1] = *(const s16x8*)&Qb[hb + (size_t)rh * 64 + 32 + g * 8];
        aqL[0] = *(const s16x8*)&Qb[hb + (size_t)rl * 64 + g * 8];
        aqL[1] = *(const s16x8*)&Qb[hb + (size_t)rl * 64 + 32 + g * 8];
    }

    float lsumH = 0.f, lsumL = 0.f;
    f32x4 OH[4], OL[4];                      // O^T: row d = nt*16+l15, col query
    #pragma unroll
    for (int nt = 0; nt < 4; ++nt) { OH[nt] = (f32x4){0.f,0.f,0.f,0.f}; OL[nt] = (f32x4){0.f,0.f,0.f,0.f}; }

    const int stages      = 32 - 2 * j;
    const int lightStages = 2 * j + 2;

    const int srow = tid >> 3, spart = tid & 7;
    uint4 kreg = *(const uint4*)&Kb[hb + (size_t)srow * 64 + spart * 8];
    uint4 vreg = *(const uint4*)&Vt[hb + (size_t)srow * 2048 + spart * 8];

    for (int t = 0; t < stages; ++t) {
        const int t0  = t * 64;
        const int buf = t & 1;
        *(uint4*)&Kls[buf][srow * LDK + spart * 8] = kreg;
        *(uint4*)&Vls[buf][srow * LDK + spart * 8] = vreg;
        if (t + 1 < stages) {
            kreg = *(const uint4*)&Kb[hb + (size_t)(t0 + 64 + srow) * 64 + spart * 8];
            vreg = *(const uint4*)&Vt[hb + (size_t)srow * 2048 + t0 + 64 + spart * 8];
        }
        __syncthreads();

        #pragma unroll
        for (int half = 0; half < 2; ++half) {
            if (half == 1 && t >= lightStages) break;
            const s16x8* aq   = (half == 0) ? aqH : aqL;
            const int qbase   = (half == 0) ? qH : qL;
            f32x4* Oacc       = (half == 0) ? OH : OL;

            // ---- S^T = K * Q^T : Sf[ct][r] = S[query=l15][key=t0+ct*16+g*4+r]
            f32x4 Sf[4];
            #pragma unroll
            for (int ct = 0; ct < 4; ++ct) {
                f32x4 acc = (f32x4){0.f, 0.f, 0.f, 0.f};
                const s16x8 bk0 = *(const s16x8*)&Kls[buf][(ct * 16 + l15) * LDK + g * 8];
                const s16x8 bk1 = *(const s16x8*)&Kls[buf][(ct * 16 + l15) * LDK + 32 + g * 8];
                acc = __builtin_amdgcn_mfma_f32_16x16x32_bf16(bk0, aq[0], acc, 0, 0, 0);
                acc = __builtin_amdgcn_mfma_f32_16x16x32_bf16(bk1, aq[1], acc, 0, 0, 0);
                Sf[ct] = acc;
            }

            // ---- causal mask (diagonal tiles only) ----
            if (t0 + 63 > qbase) {
                const int query = qbase + l15;
                #pragma unroll
                for (int ct = 0; ct < 4; ++ct) {
                    const int kbase = t0 + ct * 16 + g * 4;
                    #pragma unroll
                    for (int r = 0; r < 4; ++r)
                        if (kbase + r > query) Sf[ct][r] = -1e30f;
                }
            }

            // ---- p = exp2(s); partial row-sum ----
            float lacc = 0.f;
            #pragma unroll
            for (int ct = 0; ct < 4; ++ct) {
                #pragma unroll
                for (int r = 0; r < 4; ++r) Sf[ct][r] = exp2f(Sf[ct][r]);
                lacc += (Sf[ct][0] + Sf[ct][1]) + (Sf[ct][2] + Sf[ct][3]);
            }
            if (half == 0) lsumH += lacc; else lsumL += lacc;

            // ---- write P[query][key]: 4 consecutive keys per lane -> b64 ----
            #pragma unroll
            for (int ct = 0; ct < 4; ++ct) {
                uint2 pw;
                pw.x = pack_bf2(Sf[ct][0], Sf[ct][1]);
                pw.y = pack_bf2(Sf[ct][2], Sf[ct][3]);
                *(uint2*)&Pls[w][l15 * LDK + ct * 16 + g * 4] = pw;
            }

            // ---- PV: O^T += V^T * P^T (B-frag = b128 read of P row) ----
            const s16x8 pf0 = *(const s16x8*)&Pls[w][l15 * LDK + g * 8];
            const s16x8 pf1 = *(const s16x8*)&Pls[w][l15 * LDK + 32 + g * 8];
            #pragma unroll
            for (int nt = 0; nt < 4; ++nt) {
                const s16x8 bv0 = *(const s16x8*)&Vls[buf][(nt * 16 + l15) * LDK + g * 8];
                const s16x8 bv1 = *(const s16x8*)&Vls[buf][(nt * 16 + l15) * LDK + 32 + g * 8];
                Oacc[nt] = __builtin_amdgcn_mfma_f32_16x16x32_bf16(bv0, pf0, Oacc[nt], 0, 0, 0);
                Oacc[nt] = __builtin_amdgcn_mfma_f32_16x16x32_bf16(bv1, pf1, Oacc[nt], 0, 0, 0);
            }
        }
    }

    // ---- epilogue: finish l reduction (across the 4 quads), store O ----
    lsumH += __shfl_xor(lsumH, 16);
    lsumH += __shfl_xor(lsumH, 32);
    lsumL += __shfl_xor(lsumL, 16);
    lsumL += __shfl_xor(lsumL, 32);
    const float invH = 1.0f / lsumH;
    const float invL = 1.0f / lsumL;

    #pragma unroll
    for (int half = 0; half < 2; ++half) {
        const f32x4* Oacc = (half == 0) ? OH : OL;
        const float  inv  = (half == 0) ? invH : invL;
        const int query   = ((half == 0) ? qH : qL) + l15;
        #pragma unroll
        for (int nt = 0; nt < 4; ++nt) {
            uint2 pk;
            pk.x = pack_bf2(Oacc[nt][0] * inv, Oacc[nt][1] * inv);
            pk.y = pack_bf2(Oacc[nt][2] * inv, Oacc[nt][3] * inv);
            *(uint2*)&O[(size_t)(b * 2048 + query) * 1024 + h * 64 + nt * 16 + g * 4] = pk;
        }
    }
}

// ---------------------------------------------------------------------------
// ws (ushort elems): xb 8M | Wqkvt 3M | Wot 1M | Qb/Kb/Vt 8M each | Ob 8M
// ---------------------------------------------------------------------------
extern "C" void kernel_launch(void* const* d_in, const int* in_sizes, int n_in,
                              void* d_out, int out_size, void* d_ws, size_t ws_size,
                              hipStream_t stream) {
    const float* x  = (const float*)d_in[0];
    const float* wq = (const float*)d_in[1];
    const float* bq = (const float*)d_in[2];
    const float* wk = (const float*)d_in[3];
    const float* bk = (const float*)d_in[4];
    const float* wv = (const float*)d_in[5];
    const float* bv = (const float*)d_in[6];
    const float* wo = (const float*)d_in[7];
    const float* bo = (const float*)d_in[8];
    float* out = (float*)d_out;

    const size_t hsz = (size_t)B_ * H_ * S_ * D_;        // 8388608
    unsigned short* xb    = (unsigned short*)d_ws;
    unsigned short* Wqkvt = xb + hsz;
    unsigned short* Wot   = Wqkvt + (size_t)3072 * 1024;
    unsigned short* Qb    = Wot + (size_t)1024 * 1024;
    unsigned short* Kb    = Qb + hsz;
    unsigned short* Vt    = Kb + hsz;
    unsigned short* Ob    = Vt + hsz;

    cast_x<<<4096, 256, 0, stream>>>(x, xb);
    transpose_w<<<dim3(16, 16, 49), 256, 0, stream>>>(wq, wk, wv, wo, Wqkvt, Wot);
    gemm_mfma<0><<<dim3(32, 16), 512, 0, stream>>>(
        xb, Wqkvt, bq, bk, bv, nullptr, Qb, Kb, Vt, nullptr);
    attn_mfma<<<dim3(8, H_, B_), 512, 0, stream>>>(Qb, Kb, Vt, Ob);
    gemm_mfma<1><<<dim3(64, 4), 512, 0, stream>>>(
        Ob, Wot, nullptr, nullptr, nullptr, bo, nullptr, nullptr, nullptr, out);
}

// Round 3
// 271.816 us; speedup vs baseline: 1.1364x; 1.1149x over previous
//
#include <hip/hip_runtime.h>
#include <math.h>

#define B_ 4
#define S_ 2048
#define E_ 1024
#define H_ 16
#define D_ 64

using f32x4 = __attribute__((ext_vector_type(4))) float;
using s16x8 = __attribute__((ext_vector_type(8))) short;

// fp32 -> bf16 bits, round-to-nearest-even
__device__ __forceinline__ unsigned short f2bf(float f) {
    unsigned int u = __float_as_uint(f);
    u = (u + 0x7FFFu + ((u >> 16) & 1u)) >> 16;
    return (unsigned short)u;
}

// pack hi16(a)|hi16(b)<<16 with +0x8000 rounding (round-half-up, 3 VALU ops)
__device__ __forceinline__ unsigned int pack_bf2(float lo, float hi) {
    const unsigned int ulo = __float_as_uint(lo) + 0x8000u;
    const unsigned int uhi = __float_as_uint(hi) + 0x8000u;
    return __builtin_amdgcn_perm(uhi, ulo, 0x07060302u);
}

// async global->LDS DMA, 16B per lane; LDS dest = wave-uniform base + lane*16
__device__ __forceinline__ void load_lds16(const void* g, void* l) {
    __builtin_amdgcn_global_load_lds(
        (const __attribute__((address_space(1))) void*)g,
        (__attribute__((address_space(3))) void*)l, 16, 0, 0);
}

#define WAITV(n) asm volatile("s_waitcnt vmcnt(" #n ")" ::: "memory")

// Q pre-scale: 1/sqrt(D) * log2(e) -> softmax in base-2 (native v_exp_f32)
#define QSCALE 0.18033688011112042f

// ---------------------------------------------------------------------------
// x (fp32 [8192][1024]) -> bf16, same layout.
// ---------------------------------------------------------------------------
__global__ __launch_bounds__(256)
void cast_x(const float* __restrict__ in, unsigned short* __restrict__ out)
{
    const size_t idx = (size_t)blockIdx.x * 2048 + threadIdx.x * 8;
    const float4 v0 = *(const float4*)&in[idx];
    const float4 v1 = *(const float4*)&in[idx + 4];
    uint4 p;
    p.x = (unsigned)f2bf(v0.x) | ((unsigned)f2bf(v0.y) << 16);
    p.y = (unsigned)f2bf(v0.z) | ((unsigned)f2bf(v0.w) << 16);
    p.z = (unsigned)f2bf(v1.x) | ((unsigned)f2bf(v1.y) << 16);
    p.w = (unsigned)f2bf(v1.z) | ((unsigned)f2bf(v1.w) << 16);
    *(uint4*)&out[idx] = p;
}

// ---------------------------------------------------------------------------
// Weight transpose + bf16 cast (unchanged).
// ---------------------------------------------------------------------------
__global__ __launch_bounds__(256)
void transpose_w(const float* __restrict__ wq, const float* __restrict__ wk,
                 const float* __restrict__ wv, const float* __restrict__ wo,
                 unsigned short* __restrict__ Wqkvt, unsigned short* __restrict__ Wot)
{
    __shared__ float T[64][68];
    const int z = blockIdx.z;
    const float* in;
    unsigned short* out;
    int inStride, r0, c0;
    if (z < 48) {
        if (blockIdx.y != 0) return;
        const int t = z >> 4, h = z & 15;
        const float* W = (t == 0) ? wq : ((t == 1) ? wk : wv);
        in = W + (size_t)h * (E_ * D_);
        inStride = 64;
        out = Wqkvt + (size_t)(t * 1024 + h * 64) * 1024;
        r0 = blockIdx.x * 64; c0 = 0;
    } else {
        in = wo; inStride = 1024;
        out = Wot;
        r0 = blockIdx.x * 64; c0 = blockIdx.y * 64;
    }
    const int tid = threadIdx.x;
    #pragma unroll
    for (int i = 0; i < 4; ++i) {
        const int e = tid + i * 256;
        const int row = e >> 4, c4 = e & 15;
        const float4 v = *(const float4*)&in[(size_t)(r0 + row) * inStride + c0 + c4 * 4];
        T[row][c4 * 4 + 0] = v.x; T[row][c4 * 4 + 1] = v.y;
        T[row][c4 * 4 + 2] = v.z; T[row][c4 * 4 + 3] = v.w;
    }
    __syncthreads();
    #pragma unroll
    for (int i = 0; i < 2; ++i) {
        const int e = tid + i * 256;
        const int c = e >> 3, ch = e & 7;
        unsigned short h8[8];
        #pragma unroll
        for (int j = 0; j < 8; ++j) h8[j] = f2bf(T[ch * 8 + j][c]);
        uint4 p;
        p.x = (unsigned)h8[0] | ((unsigned)h8[1] << 16);
        p.y = (unsigned)h8[2] | ((unsigned)h8[3] << 16);
        p.z = (unsigned)h8[4] | ((unsigned)h8[5] << 16);
        p.w = (unsigned)h8[6] | ((unsigned)h8[7] << 16);
        *(uint4*)&out[(size_t)(c0 + c) * 1024 + r0 + ch * 8] = p;
    }
}

// ---------------------------------------------------------------------------
// bf16 MFMA GEMM v6 — m201-style phase schedule (T2+T3+T4+T5), plain HIP.
//   BM=128, BN=256, BK=64, 8 waves (2M x 4N), per-wave 64x64 output.
//   LDS: 3 buffers x (A 16KB + B 32KB) = 144 KB -> 2-K-tile prefetch depth.
//   Staging: unit = 8 rows x 64 cols (1KB = one global_load_lds per wave);
//   A: 16 units (2/wave), B: 32 units (4/wave) -> 6 loads/wave/K-tile,
//   UNIFORM across waves so counted vmcnt is exact: steady state 12 in
//   flight, WAITV(6) at tile top retires exactly tile-t's loads (t+1 flies).
//   Swizzle (128B rows): LDS slot p of row r holds global chunk p^(r&7);
//   store side achieves this with linear LDS dest + pre-swizzled source
//   (chunk (l&7)^(l>>3)); read side pc = (ks*4+g)^(l15&7) -> every 8-lane
//   b128 group covers all 32 banks. Conflict-free both sides.
//   Per phase: {8 ds_read_b128 || 3 global_load_lds -> barrier ->
//   setprio(1) 16 MFMA setprio(0) -> barrier}; 2 phases (ks=0,1)/K-tile.
// MODE 0: QKV — grid 64x12 = 768 = 3 exact CU rounds.
// MODE 1: out — grid 64x4 = 256 = 1 exact CU round.
// ---------------------------------------------------------------------------
template<int MODE>
__global__ __launch_bounds__(512, 2)
void gemm_mfma(const unsigned short* __restrict__ A,
               const unsigned short* __restrict__ Bt,
               const float* __restrict__ bq, const float* __restrict__ bk,
               const float* __restrict__ bv, const float* __restrict__ bo,
               unsigned short* __restrict__ Qb, unsigned short* __restrict__ Kb,
               unsigned short* __restrict__ Vt, float* __restrict__ Cout)
{
    __shared__ short As[3][128 * 64];
    __shared__ short Bs[3][256 * 64];

    const int tid  = threadIdx.x;
    const int w    = tid >> 6, lane = tid & 63;
    const int g    = lane >> 4, l15 = lane & 15;
    const int wm   = w >> 2, wn = w & 3;
    const int mbase = blockIdx.x * 128;
    const int nbase = blockIdx.y * 256;

    // staging source pre-swizzle: lane l covers row (l>>3), chunk (l&7)^(l>>3)
    const int srow   = lane >> 3;                 // 0..7 row within unit
    const int schunk = (lane & 7) ^ srow;         // pre-swizzled source chunk
    const size_t aoff = (size_t)(mbase + srow) * 1024 + schunk * 8;
    const size_t boff = (size_t)(nbase + srow) * 1024 + schunk * 8;

    f32x4 acc[4][4];
    #pragma unroll
    for (int mt = 0; mt < 4; ++mt)
        #pragma unroll
        for (int nt = 0; nt < 4; ++nt)
            acc[mt][nt] = (f32x4){0.f, 0.f, 0.f, 0.f};

    // one A staging unit: u = w*2+i (i=0..1); one B unit: u = w*4+i (i=0..3)
    auto STAGE_A = [&](int t, int buf, int i) {
        const int u = w * 2 + i;
        load_lds16(&A[aoff + (size_t)(u * 8) * 1024 + t * 64], &As[buf][u * 512]);
    };
    auto STAGE_B = [&](int t, int buf, int i) {
        const int u = w * 4 + i;
        load_lds16(&Bt[boff + (size_t)(u * 8) * 1024 + t * 64], &Bs[buf][u * 512]);
    };
    // fixed per-tile issue order (same for prologue & loop): A0 A1 B0 B1 B2 B3

    // prologue: tiles 0 and 1 fully staged
    STAGE_A(0, 0, 0); STAGE_A(0, 0, 1);
    STAGE_B(0, 0, 0); STAGE_B(0, 0, 1); STAGE_B(0, 0, 2); STAGE_B(0, 0, 3);
    STAGE_A(1, 1, 0); STAGE_A(1, 1, 1);
    STAGE_B(1, 1, 0); STAGE_B(1, 1, 1); STAGE_B(1, 1, 2); STAGE_B(1, 1, 3);

    const int pr = l15 & 7;                       // read-side row swizzle bits

    #pragma unroll 1
    for (int t = 0; t < 16; ++t) {
        const int buf = t % 3;
        const int nb  = (t + 2) % 3;
        // retire exactly tile-t's 6 loads; keep t+1's 6 in flight
        if (t < 15) { WAITV(6); } else { WAITV(0); }
        __builtin_amdgcn_s_barrier();             // publish tile t across waves
        __builtin_amdgcn_sched_barrier(0);

        s16x8 af[4], bf[4];

        // ---- phase 0 (ks=0): reads + A-staging, then MFMA cluster ----
        {
            const int pc = (g ^ pr) * 8;          // chunk ks*4+g = g, swizzled
            #pragma unroll
            for (int mt = 0; mt < 4; ++mt)
                af[mt] = *(const s16x8*)&As[buf][(wm * 64 + mt * 16 + l15) * 64 + pc];
            #pragma unroll
            for (int nt = 0; nt < 4; ++nt)
                bf[nt] = *(const s16x8*)&Bs[buf][(wn * 64 + nt * 16 + l15) * 64 + pc];
        }
        if (t + 2 < 16) { STAGE_A(t + 2, nb, 0); STAGE_A(t + 2, nb, 1); STAGE_B(t + 2, nb, 0); }
        __builtin_amdgcn_s_barrier();
        __builtin_amdgcn_sched_barrier(0);
        __builtin_amdgcn_s_setprio(1);
        #pragma unroll
        for (int mt = 0; mt < 4; ++mt)
            #pragma unroll
            for (int nt = 0; nt < 4; ++nt)
                acc[mt][nt] = __builtin_amdgcn_mfma_f32_16x16x32_bf16(
                    af[mt], bf[nt], acc[mt][nt], 0, 0, 0);
        __builtin_amdgcn_s_setprio(0);
        __builtin_amdgcn_s_barrier();

        // ---- phase 1 (ks=1): reads + B-staging, then MFMA cluster ----
        {
            const int pc = ((4 + g) ^ pr) * 8;    // chunk 4+g, swizzled
            #pragma unroll
            for (int mt = 0; mt < 4; ++mt)
                af[mt] = *(const s16x8*)&As[buf][(wm * 64 + mt * 16 + l15) * 64 + pc];
            #pragma unroll
            for (int nt = 0; nt < 4; ++nt)
                bf[nt] = *(const s16x8*)&Bs[buf][(wn * 64 + nt * 16 + l15) * 64 + pc];
        }
        if (t + 2 < 16) { STAGE_B(t + 2, nb, 1); STAGE_B(t + 2, nb, 2); STAGE_B(t + 2, nb, 3); }
        __builtin_amdgcn_s_barrier();
        __builtin_amdgcn_sched_barrier(0);
        __builtin_amdgcn_s_setprio(1);
        #pragma unroll
        for (int mt = 0; mt < 4; ++mt)
            #pragma unroll
            for (int nt = 0; nt < 4; ++nt)
                acc[mt][nt] = __builtin_amdgcn_mfma_f32_16x16x32_bf16(
                    af[mt], bf[nt], acc[mt][nt], 0, 0, 0);
        __builtin_amdgcn_s_setprio(0);
        // (phase-1 end barrier merged with next tile's top barrier)
    }

    #pragma unroll
    for (int nt = 0; nt < 4; ++nt) {
        const int ncol = nbase + wn * 64 + nt * 16 + l15;
        if (MODE == 0) {
            const int tt = ncol >> 10;
            const int hh = (ncol >> 6) & 15;
            const int d  = ncol & 63;
            const float* bias = (tt == 0) ? bq : ((tt == 1) ? bk : bv);
            const float sc = (tt == 0) ? QSCALE : 1.0f;
            const float bval = bias[hh * 64 + d];
            #pragma unroll
            for (int mt = 0; mt < 4; ++mt)
                #pragma unroll
                for (int r = 0; r < 4; ++r) {
                    const int m = mbase + wm * 64 + mt * 16 + g * 4 + r;
                    const int b = m >> 11, s = m & 2047;
                    const unsigned short val = f2bf((acc[mt][nt][r] + bval) * sc);
                    if (tt == 2)
                        Vt[((size_t)(b * 16 + hh) * 64 + d) * 2048 + s] = val;
                    else {
                        unsigned short* Out = (tt == 0) ? Qb : Kb;
                        Out[((size_t)(b * 16 + hh) * 2048 + s) * 64 + d] = val;
                    }
                }
        } else {
            const float bval = bo[ncol];
            #pragma unroll
            for (int mt = 0; mt < 4; ++mt)
                #pragma unroll
                for (int r = 0; r < 4; ++r) {
                    const int m = mbase + wm * 64 + mt * 16 + g * 4 + r;
                    Cout[(size_t)m * 1024 + ncol] = acc[mt][nt][r] + bval;
                }
        }
    }
}

// ---------------------------------------------------------------------------
// MFMA flash attention v7 (unchanged) — S^T formulation, P in LDS
// [query][key] (b64 writes / b128 reads), no online max, deferred l,
// causal pairing, K/V LDS double-buffer + register prefetch, spill-free.
// ---------------------------------------------------------------------------
#define LDK 72
__global__ __launch_bounds__(512, 2)
void attn_mfma(const unsigned short* __restrict__ Qb,
               const unsigned short* __restrict__ Kb,
               const unsigned short* __restrict__ Vt,
               unsigned short* __restrict__ O)
{
    __shared__ short Kls[2][64 * LDK];
    __shared__ short Vls[2][64 * LDK];       // [d][key]
    __shared__ short Pls[8][16 * LDK];       // per-wave P [query][key]

    const int tid  = threadIdx.x;
    const int w    = tid >> 6;               // 0..7
    const int lane = tid & 63;
    const int g    = lane >> 4;
    const int l15  = lane & 15;
    const int j    = blockIdx.x;             // 0..7 (light tile index)
    const int j2   = 15 - j;                 // heavy tile index
    const int h    = blockIdx.y;
    const int b    = blockIdx.z;

    const size_t hb = (size_t)(b * 16 + h) * (2048 * 64);
    const int qH = j2 * 128 + w * 16;        // this wave's heavy query base
    const int qL = j * 128 + w * 16;         // this wave's light query base

    s16x8 aqH[2], aqL[2];
    {
        const int rh = qH + l15, rl = qL + l15;
        aqH[0] = *(const s16x8*)&Qb[hb + (size_t)rh * 64 + g * 8];
        aqH[1] = *(const s16x8*)&Qb[hb + (size_t)rh * 64 + 32 + g * 8];
        aqL[0] = *(const s16x8*)&Qb[hb + (size_t)rl * 64 + g * 8];
        aqL[1] = *(const s16x8*)&Qb[hb + (size_t)rl * 64 + 32 + g * 8];
    }

    float lsumH = 0.f, lsumL = 0.f;
    f32x4 OH[4], OL[4];                      // O^T: row d = nt*16+l15, col query
    #pragma unroll
    for (int nt = 0; nt < 4; ++nt) { OH[nt] = (f32x4){0.f,0.f,0.f,0.f}; OL[nt] = (f32x4){0.f,0.f,0.f,0.f}; }

    const int stages      = 32 - 2 * j;
    const int lightStages = 2 * j + 2;

    const int srow = tid >> 3, spart = tid & 7;
    uint4 kreg = *(const uint4*)&Kb[hb + (size_t)srow * 64 + spart * 8];
    uint4 vreg = *(const uint4*)&Vt[hb + (size_t)srow * 2048 + spart * 8];

    for (int t = 0; t < stages; ++t) {
        const int t0  = t * 64;
        const int buf = t & 1;
        *(uint4*)&Kls[buf][srow * LDK + spart * 8] = kreg;
        *(uint4*)&Vls[buf][srow * LDK + spart * 8] = vreg;
        if (t + 1 < stages) {
            kreg = *(const uint4*)&Kb[hb + (size_t)(t0 + 64 + srow) * 64 + spart * 8];
            vreg = *(const uint4*)&Vt[hb + (size_t)srow * 2048 + t0 + 64 + spart * 8];
        }
        __syncthreads();

        #pragma unroll
        for (int half = 0; half < 2; ++half) {
            if (half == 1 && t >= lightStages) break;
            const s16x8* aq   = (half == 0) ? aqH : aqL;
            const int qbase   = (half == 0) ? qH : qL;
            f32x4* Oacc       = (half == 0) ? OH : OL;

            // ---- S^T = K * Q^T : Sf[ct][r] = S[query=l15][key=t0+ct*16+g*4+r]
            f32x4 Sf[4];
            #pragma unroll
            for (int ct = 0; ct < 4; ++ct) {
                f32x4 acc = (f32x4){0.f, 0.f, 0.f, 0.f};
                const s16x8 bk0 = *(const s16x8*)&Kls[buf][(ct * 16 + l15) * LDK + g * 8];
                const s16x8 bk1 = *(const s16x8*)&Kls[buf][(ct * 16 + l15) * LDK + 32 + g * 8];
                acc = __builtin_amdgcn_mfma_f32_16x16x32_bf16(bk0, aq[0], acc, 0, 0, 0);
                acc = __builtin_amdgcn_mfma_f32_16x16x32_bf16(bk1, aq[1], acc, 0, 0, 0);
                Sf[ct] = acc;
            }

            // ---- causal mask (diagonal tiles only) ----
            if (t0 + 63 > qbase) {
                const int query = qbase + l15;
                #pragma unroll
                for (int ct = 0; ct < 4; ++ct) {
                    const int kbase = t0 + ct * 16 + g * 4;
                    #pragma unroll
                    for (int r = 0; r < 4; ++r)
                        if (kbase + r > query) Sf[ct][r] = -1e30f;
                }
            }

            // ---- p = exp2(s); partial row-sum ----
            float lacc = 0.f;
            #pragma unroll
            for (int ct = 0; ct < 4; ++ct) {
                #pragma unroll
                for (int r = 0; r < 4; ++r) Sf[ct][r] = exp2f(Sf[ct][r]);
                lacc += (Sf[ct][0] + Sf[ct][1]) + (Sf[ct][2] + Sf[ct][3]);
            }
            if (half == 0) lsumH += lacc; else lsumL += lacc;

            // ---- write P[query][key]: 4 consecutive keys per lane -> b64 ----
            #pragma unroll
            for (int ct = 0; ct < 4; ++ct) {
                uint2 pw;
                pw.x = pack_bf2(Sf[ct][0], Sf[ct][1]);
                pw.y = pack_bf2(Sf[ct][2], Sf[ct][3]);
                *(uint2*)&Pls[w][l15 * LDK + ct * 16 + g * 4] = pw;
            }

            // ---- PV: O^T += V^T * P^T (B-frag = b128 read of P row) ----
            const s16x8 pf0 = *(const s16x8*)&Pls[w][l15 * LDK + g * 8];
            const s16x8 pf1 = *(const s16x8*)&Pls[w][l15 * LDK + 32 + g * 8];
            #pragma unroll
            for (int nt = 0; nt < 4; ++nt) {
                const s16x8 bv0 = *(const s16x8*)&Vls[buf][(nt * 16 + l15) * LDK + g * 8];
                const s16x8 bv1 = *(const s16x8*)&Vls[buf][(nt * 16 + l15) * LDK + 32 + g * 8];
                Oacc[nt] = __builtin_amdgcn_mfma_f32_16x16x32_bf16(bv0, pf0, Oacc[nt], 0, 0, 0);
                Oacc[nt] = __builtin_amdgcn_mfma_f32_16x16x32_bf16(bv1, pf1, Oacc[nt], 0, 0, 0);
            }
        }
    }

    // ---- epilogue: finish l reduction (across the 4 quads), store O ----
    lsumH += __shfl_xor(lsumH, 16);
    lsumH += __shfl_xor(lsumH, 32);
    lsumL += __shfl_xor(lsumL, 16);
    lsumL += __shfl_xor(lsumL, 32);
    const float invH = 1.0f / lsumH;
    const float invL = 1.0f / lsumL;

    #pragma unroll
    for (int half = 0; half < 2; ++half) {
        const f32x4* Oacc = (half == 0) ? OH : OL;
        const float  inv  = (half == 0) ? invH : invL;
        const int query   = ((half == 0) ? qH : qL) + l15;
        #pragma unroll
        for (int nt = 0; nt < 4; ++nt) {
            uint2 pk;
            pk.x = pack_bf2(Oacc[nt][0] * inv, Oacc[nt][1] * inv);
            pk.y = pack_bf2(Oacc[nt][2] * inv, Oacc[nt][3] * inv);
            *(uint2*)&O[(size_t)(b * 2048 + query) * 1024 + h * 64 + nt * 16 + g * 4] = pk;
        }
    }
}

// ---------------------------------------------------------------------------
// ws (ushort elems): xb 8M | Wqkvt 3M | Wot 1M | Qb/Kb/Vt 8M each | Ob 8M
// ---------------------------------------------------------------------------
extern "C" void kernel_launch(void* const* d_in, const int* in_sizes, int n_in,
                              void* d_out, int out_size, void* d_ws, size_t ws_size,
                              hipStream_t stream) {
    const float* x  = (const float*)d_in[0];
    const float* wq = (const float*)d_in[1];
    const float* bq = (const float*)d_in[2];
    const float* wk = (const float*)d_in[3];
    const float* bk = (const float*)d_in[4];
    const float* wv = (const float*)d_in[5];
    const float* bv = (const float*)d_in[6];
    const float* wo = (const float*)d_in[7];
    const float* bo = (const float*)d_in[8];
    float* out = (float*)d_out;

    const size_t hsz = (size_t)B_ * H_ * S_ * D_;        // 8388608
    unsigned short* xb    = (unsigned short*)d_ws;
    unsigned short* Wqkvt = xb + hsz;
    unsigned short* Wot   = Wqkvt + (size_t)3072 * 1024;
    unsigned short* Qb    = Wot + (size_t)1024 * 1024;
    unsigned short* Kb    = Qb + hsz;
    unsigned short* Vt    = Kb + hsz;
    unsigned short* Ob    = Vt + hsz;

    cast_x<<<4096, 256, 0, stream>>>(x, xb);
    transpose_w<<<dim3(16, 16, 49), 256, 0, stream>>>(wq, wk, wv, wo, Wqkvt, Wot);
    gemm_mfma<0><<<dim3(64, 12), 512, 0, stream>>>(
        xb, Wqkvt, bq, bk, bv, nullptr, Qb, Kb, Vt, nullptr);
    attn_mfma<<<dim3(8, H_, B_), 512, 0, stream>>>(Qb, Kb, Vt, Ob);
    gemm_mfma<1><<<dim3(64, 4), 512, 0, stream>>>(
        Ob, Wot, nullptr, nullptr, nullptr, bo, nullptr, nullptr, nullptr, out);
}

// Round 4
// 264.892 us; speedup vs baseline: 1.1661x; 1.0261x over previous
//
#include <hip/hip_runtime.h>
#include <math.h>

#define B_ 4
#define S_ 2048
#define E_ 1024
#define H_ 16
#define D_ 64

using f32x4 = __attribute__((ext_vector_type(4))) float;
using s16x8 = __attribute__((ext_vector_type(8))) short;

// fp32 -> bf16 bits, round-to-nearest-even
__device__ __forceinline__ unsigned short f2bf(float f) {
    unsigned int u = __float_as_uint(f);
    u = (u + 0x7FFFu + ((u >> 16) & 1u)) >> 16;
    return (unsigned short)u;
}

// pack two fp32 -> one u32 of 2x bf16 (RNE) in ONE VALU op (T12 primitive)
__device__ __forceinline__ unsigned int cvt_pk_bf16(float lo, float hi) {
    unsigned int r;
    asm("v_cvt_pk_bf16_f32 %0, %1, %2" : "=v"(r) : "v"(lo), "v"(hi));
    return r;
}

// raw 2^x (avoid libm range-fixup ops if builtin available)
__device__ __forceinline__ float fast_exp2(float x) {
#if __has_builtin(__builtin_amdgcn_exp2f)
    return __builtin_amdgcn_exp2f(x);
#else
    return exp2f(x);
#endif
}

// async global->LDS DMA, 16B per lane; LDS dest = wave-uniform base + lane*16
__device__ __forceinline__ void load_lds16(const void* g, void* l) {
    __builtin_amdgcn_global_load_lds(
        (const __attribute__((address_space(1))) void*)g,
        (__attribute__((address_space(3))) void*)l, 16, 0, 0);
}

#define WAITV(n) asm volatile("s_waitcnt vmcnt(" #n ")" ::: "memory")

// Q pre-scale: 1/sqrt(D) * log2(e) -> softmax in base-2 (native v_exp_f32)
#define QSCALE 0.18033688011112042f

// ---------------------------------------------------------------------------
// x (fp32 [8192][1024]) -> bf16, same layout.
// ---------------------------------------------------------------------------
__global__ __launch_bounds__(256)
void cast_x(const float* __restrict__ in, unsigned short* __restrict__ out)
{
    const size_t idx = (size_t)blockIdx.x * 2048 + threadIdx.x * 8;
    const float4 v0 = *(const float4*)&in[idx];
    const float4 v1 = *(const float4*)&in[idx + 4];
    uint4 p;
    p.x = (unsigned)f2bf(v0.x) | ((unsigned)f2bf(v0.y) << 16);
    p.y = (unsigned)f2bf(v0.z) | ((unsigned)f2bf(v0.w) << 16);
    p.z = (unsigned)f2bf(v1.x) | ((unsigned)f2bf(v1.y) << 16);
    p.w = (unsigned)f2bf(v1.z) | ((unsigned)f2bf(v1.w) << 16);
    *(uint4*)&out[idx] = p;
}

// ---------------------------------------------------------------------------
// Weight transpose + bf16 cast (unchanged).
// ---------------------------------------------------------------------------
__global__ __launch_bounds__(256)
void transpose_w(const float* __restrict__ wq, const float* __restrict__ wk,
                 const float* __restrict__ wv, const float* __restrict__ wo,
                 unsigned short* __restrict__ Wqkvt, unsigned short* __restrict__ Wot)
{
    __shared__ float T[64][68];
    const int z = blockIdx.z;
    const float* in;
    unsigned short* out;
    int inStride, r0, c0;
    if (z < 48) {
        if (blockIdx.y != 0) return;
        const int t = z >> 4, h = z & 15;
        const float* W = (t == 0) ? wq : ((t == 1) ? wk : wv);
        in = W + (size_t)h * (E_ * D_);
        inStride = 64;
        out = Wqkvt + (size_t)(t * 1024 + h * 64) * 1024;
        r0 = blockIdx.x * 64; c0 = 0;
    } else {
        in = wo; inStride = 1024;
        out = Wot;
        r0 = blockIdx.x * 64; c0 = blockIdx.y * 64;
    }
    const int tid = threadIdx.x;
    #pragma unroll
    for (int i = 0; i < 4; ++i) {
        const int e = tid + i * 256;
        const int row = e >> 4, c4 = e & 15;
        const float4 v = *(const float4*)&in[(size_t)(r0 + row) * inStride + c0 + c4 * 4];
        T[row][c4 * 4 + 0] = v.x; T[row][c4 * 4 + 1] = v.y;
        T[row][c4 * 4 + 2] = v.z; T[row][c4 * 4 + 3] = v.w;
    }
    __syncthreads();
    #pragma unroll
    for (int i = 0; i < 2; ++i) {
        const int e = tid + i * 256;
        const int c = e >> 3, ch = e & 7;
        unsigned short h8[8];
        #pragma unroll
        for (int j = 0; j < 8; ++j) h8[j] = f2bf(T[ch * 8 + j][c]);
        uint4 p;
        p.x = (unsigned)h8[0] | ((unsigned)h8[1] << 16);
        p.y = (unsigned)h8[2] | ((unsigned)h8[3] << 16);
        p.z = (unsigned)h8[4] | ((unsigned)h8[5] << 16);
        p.w = (unsigned)h8[6] | ((unsigned)h8[7] << 16);
        *(uint4*)&out[(size_t)(c0 + c) * 1024 + r0 + ch * 8] = p;
    }
}

// ---------------------------------------------------------------------------
// bf16 MFMA GEMM v6 — m201-style phase schedule (T2+T3+T4+T5) — unchanged
// from R3 (verified: both GEMM dispatches dropped off the top-5).
// ---------------------------------------------------------------------------
template<int MODE>
__global__ __launch_bounds__(512, 2)
void gemm_mfma(const unsigned short* __restrict__ A,
               const unsigned short* __restrict__ Bt,
               const float* __restrict__ bq, const float* __restrict__ bk,
               const float* __restrict__ bv, const float* __restrict__ bo,
               unsigned short* __restrict__ Qb, unsigned short* __restrict__ Kb,
               unsigned short* __restrict__ Vt, float* __restrict__ Cout)
{
    __shared__ short As[3][128 * 64];
    __shared__ short Bs[3][256 * 64];

    const int tid  = threadIdx.x;
    const int w    = tid >> 6, lane = tid & 63;
    const int g    = lane >> 4, l15 = lane & 15;
    const int wm   = w >> 2, wn = w & 3;
    const int mbase = blockIdx.x * 128;
    const int nbase = blockIdx.y * 256;

    const int srow   = lane >> 3;                 // 0..7 row within unit
    const int schunk = (lane & 7) ^ srow;         // pre-swizzled source chunk
    const size_t aoff = (size_t)(mbase + srow) * 1024 + schunk * 8;
    const size_t boff = (size_t)(nbase + srow) * 1024 + schunk * 8;

    f32x4 acc[4][4];
    #pragma unroll
    for (int mt = 0; mt < 4; ++mt)
        #pragma unroll
        for (int nt = 0; nt < 4; ++nt)
            acc[mt][nt] = (f32x4){0.f, 0.f, 0.f, 0.f};

    auto STAGE_A = [&](int t, int buf, int i) {
        const int u = w * 2 + i;
        load_lds16(&A[aoff + (size_t)(u * 8) * 1024 + t * 64], &As[buf][u * 512]);
    };
    auto STAGE_B = [&](int t, int buf, int i) {
        const int u = w * 4 + i;
        load_lds16(&Bt[boff + (size_t)(u * 8) * 1024 + t * 64], &Bs[buf][u * 512]);
    };

    STAGE_A(0, 0, 0); STAGE_A(0, 0, 1);
    STAGE_B(0, 0, 0); STAGE_B(0, 0, 1); STAGE_B(0, 0, 2); STAGE_B(0, 0, 3);
    STAGE_A(1, 1, 0); STAGE_A(1, 1, 1);
    STAGE_B(1, 1, 0); STAGE_B(1, 1, 1); STAGE_B(1, 1, 2); STAGE_B(1, 1, 3);

    const int pr = l15 & 7;

    #pragma unroll 1
    for (int t = 0; t < 16; ++t) {
        const int buf = t % 3;
        const int nb  = (t + 2) % 3;
        if (t < 15) { WAITV(6); } else { WAITV(0); }
        __builtin_amdgcn_s_barrier();
        __builtin_amdgcn_sched_barrier(0);

        s16x8 af[4], bf[4];

        {
            const int pc = (g ^ pr) * 8;
            #pragma unroll
            for (int mt = 0; mt < 4; ++mt)
                af[mt] = *(const s16x8*)&As[buf][(wm * 64 + mt * 16 + l15) * 64 + pc];
            #pragma unroll
            for (int nt = 0; nt < 4; ++nt)
                bf[nt] = *(const s16x8*)&Bs[buf][(wn * 64 + nt * 16 + l15) * 64 + pc];
        }
        if (t + 2 < 16) { STAGE_A(t + 2, nb, 0); STAGE_A(t + 2, nb, 1); STAGE_B(t + 2, nb, 0); }
        __builtin_amdgcn_s_barrier();
        __builtin_amdgcn_sched_barrier(0);
        __builtin_amdgcn_s_setprio(1);
        #pragma unroll
        for (int mt = 0; mt < 4; ++mt)
            #pragma unroll
            for (int nt = 0; nt < 4; ++nt)
                acc[mt][nt] = __builtin_amdgcn_mfma_f32_16x16x32_bf16(
                    af[mt], bf[nt], acc[mt][nt], 0, 0, 0);
        __builtin_amdgcn_s_setprio(0);
        __builtin_amdgcn_s_barrier();

        {
            const int pc = ((4 + g) ^ pr) * 8;
            #pragma unroll
            for (int mt = 0; mt < 4; ++mt)
                af[mt] = *(const s16x8*)&As[buf][(wm * 64 + mt * 16 + l15) * 64 + pc];
            #pragma unroll
            for (int nt = 0; nt < 4; ++nt)
                bf[nt] = *(const s16x8*)&Bs[buf][(wn * 64 + nt * 16 + l15) * 64 + pc];
        }
        if (t + 2 < 16) { STAGE_B(t + 2, nb, 1); STAGE_B(t + 2, nb, 2); STAGE_B(t + 2, nb, 3); }
        __builtin_amdgcn_s_barrier();
        __builtin_amdgcn_sched_barrier(0);
        __builtin_amdgcn_s_setprio(1);
        #pragma unroll
        for (int mt = 0; mt < 4; ++mt)
            #pragma unroll
            for (int nt = 0; nt < 4; ++nt)
                acc[mt][nt] = __builtin_amdgcn_mfma_f32_16x16x32_bf16(
                    af[mt], bf[nt], acc[mt][nt], 0, 0, 0);
        __builtin_amdgcn_s_setprio(0);
    }

    #pragma unroll
    for (int nt = 0; nt < 4; ++nt) {
        const int ncol = nbase + wn * 64 + nt * 16 + l15;
        if (MODE == 0) {
            const int tt = ncol >> 10;
            const int hh = (ncol >> 6) & 15;
            const int d  = ncol & 63;
            const float* bias = (tt == 0) ? bq : ((tt == 1) ? bk : bv);
            const float sc = (tt == 0) ? QSCALE : 1.0f;
            const float bval = bias[hh * 64 + d];
            #pragma unroll
            for (int mt = 0; mt < 4; ++mt)
                #pragma unroll
                for (int r = 0; r < 4; ++r) {
                    const int m = mbase + wm * 64 + mt * 16 + g * 4 + r;
                    const int b = m >> 11, s = m & 2047;
                    const unsigned short val = f2bf((acc[mt][nt][r] + bval) * sc);
                    if (tt == 2)
                        Vt[((size_t)(b * 16 + hh) * 64 + d) * 2048 + s] = val;
                    else {
                        unsigned short* Out = (tt == 0) ? Qb : Kb;
                        Out[((size_t)(b * 16 + hh) * 2048 + s) * 64 + d] = val;
                    }
                }
        } else {
            const float bval = bo[ncol];
            #pragma unroll
            for (int mt = 0; mt < 4; ++mt)
                #pragma unroll
                for (int r = 0; r < 4; ++r) {
                    const int m = mbase + wm * 64 + mt * 16 + g * 4 + r;
                    Cout[(size_t)m * 1024 + ncol] = acc[mt][nt][r] + bval;
                }
        }
    }
}

// ---------------------------------------------------------------------------
// MFMA flash attention v8 — VALU-trim round.
//   R3 counters: VALUBusy 55% > MfmaUtil 19% -> VALU-bound. Cuts:
//   (1) P/O bf16 pack via v_cvt_pk_bf16_f32 (1 VALU vs 3; RNE, unbiased).
//   (2) row-sum l = P*1 via ones-MFMA: accumulate mfma(ones, pf0/pf1, lsum)
//       reusing the already-loaded P B-frags; kills the 15-add tree per half
//       AND the epilogue cross-quad shuffles (every acc reg = full l[query]).
//       Denominator now uses bf16(P), consistent with the PV numerator.
//   (3) exp2 via raw v_exp_f32 builtin (guarded).
//   Everything else (S^T formulation, P in LDS, K/V double-buffer with
//   register prefetch, causal pairing) unchanged.
// ---------------------------------------------------------------------------
#define LDK 72
__global__ __launch_bounds__(512, 2)
void attn_mfma(const unsigned short* __restrict__ Qb,
               const unsigned short* __restrict__ Kb,
               const unsigned short* __restrict__ Vt,
               unsigned short* __restrict__ O)
{
    __shared__ short Kls[2][64 * LDK];
    __shared__ short Vls[2][64 * LDK];       // [d][key]
    __shared__ short Pls[8][16 * LDK];       // per-wave P [query][key]

    const int tid  = threadIdx.x;
    const int w    = tid >> 6;               // 0..7
    const int lane = tid & 63;
    const int g    = lane >> 4;
    const int l15  = lane & 15;
    const int j    = blockIdx.x;             // 0..7 (light tile index)
    const int j2   = 15 - j;                 // heavy tile index
    const int h    = blockIdx.y;
    const int b    = blockIdx.z;

    const size_t hb = (size_t)(b * 16 + h) * (2048 * 64);
    const int qH = j2 * 128 + w * 16;        // this wave's heavy query base
    const int qL = j * 128 + w * 16;         // this wave's light query base

    s16x8 aqH[2], aqL[2];
    {
        const int rh = qH + l15, rl = qL + l15;
        aqH[0] = *(const s16x8*)&Qb[hb + (size_t)rh * 64 + g * 8];
        aqH[1] = *(const s16x8*)&Qb[hb + (size_t)rh * 64 + 32 + g * 8];
        aqL[0] = *(const s16x8*)&Qb[hb + (size_t)rl * 64 + g * 8];
        aqL[1] = *(const s16x8*)&Qb[hb + (size_t)rl * 64 + 32 + g * 8];
    }

    // all-ones bf16 A-frag for the row-sum MFMA (bf16 1.0 = 0x3F80)
    const s16x8 ones = (s16x8){(short)0x3F80, (short)0x3F80, (short)0x3F80,
                               (short)0x3F80, (short)0x3F80, (short)0x3F80,
                               (short)0x3F80, (short)0x3F80};

    f32x4 lsumHa = (f32x4){0.f,0.f,0.f,0.f};
    f32x4 lsumLa = (f32x4){0.f,0.f,0.f,0.f};
    f32x4 OH[4], OL[4];                      // O^T: col query, rows d
    #pragma unroll
    for (int nt = 0; nt < 4; ++nt) { OH[nt] = (f32x4){0.f,0.f,0.f,0.f}; OL[nt] = (f32x4){0.f,0.f,0.f,0.f}; }

    const int stages      = 32 - 2 * j;
    const int lightStages = 2 * j + 2;

    const int srow = tid >> 3, spart = tid & 7;
    uint4 kreg = *(const uint4*)&Kb[hb + (size_t)srow * 64 + spart * 8];
    uint4 vreg = *(const uint4*)&Vt[hb + (size_t)srow * 2048 + spart * 8];

    for (int t = 0; t < stages; ++t) {
        const int t0  = t * 64;
        const int buf = t & 1;
        *(uint4*)&Kls[buf][srow * LDK + spart * 8] = kreg;
        *(uint4*)&Vls[buf][srow * LDK + spart * 8] = vreg;
        if (t + 1 < stages) {
            kreg = *(const uint4*)&Kb[hb + (size_t)(t0 + 64 + srow) * 64 + spart * 8];
            vreg = *(const uint4*)&Vt[hb + (size_t)srow * 2048 + t0 + 64 + spart * 8];
        }
        __syncthreads();

        #pragma unroll
        for (int half = 0; half < 2; ++half) {
            if (half == 1 && t >= lightStages) break;
            const s16x8* aq   = (half == 0) ? aqH : aqL;
            const int qbase   = (half == 0) ? qH : qL;
            f32x4* Oacc       = (half == 0) ? OH : OL;
            f32x4* lsa        = (half == 0) ? &lsumHa : &lsumLa;

            // ---- S^T = K * Q^T : Sf[ct][r] = S[query=l15][key=t0+ct*16+g*4+r]
            f32x4 Sf[4];
            #pragma unroll
            for (int ct = 0; ct < 4; ++ct) {
                f32x4 acc = (f32x4){0.f, 0.f, 0.f, 0.f};
                const s16x8 bk0 = *(const s16x8*)&Kls[buf][(ct * 16 + l15) * LDK + g * 8];
                const s16x8 bk1 = *(const s16x8*)&Kls[buf][(ct * 16 + l15) * LDK + 32 + g * 8];
                acc = __builtin_amdgcn_mfma_f32_16x16x32_bf16(bk0, aq[0], acc, 0, 0, 0);
                acc = __builtin_amdgcn_mfma_f32_16x16x32_bf16(bk1, aq[1], acc, 0, 0, 0);
                Sf[ct] = acc;
            }

            // ---- causal mask (diagonal tiles only) ----
            if (t0 + 63 > qbase) {
                const int query = qbase + l15;
                #pragma unroll
                for (int ct = 0; ct < 4; ++ct) {
                    const int kbase = t0 + ct * 16 + g * 4;
                    #pragma unroll
                    for (int r = 0; r < 4; ++r)
                        if (kbase + r > query) Sf[ct][r] = -1e30f;
                }
            }

            // ---- p = exp2(s) ----
            #pragma unroll
            for (int ct = 0; ct < 4; ++ct)
                #pragma unroll
                for (int r = 0; r < 4; ++r) Sf[ct][r] = fast_exp2(Sf[ct][r]);

            // ---- write P[query][key]: cvt_pk (1 VALU per pair) -> b64 ----
            #pragma unroll
            for (int ct = 0; ct < 4; ++ct) {
                uint2 pw;
                pw.x = cvt_pk_bf16(Sf[ct][0], Sf[ct][1]);
                pw.y = cvt_pk_bf16(Sf[ct][2], Sf[ct][3]);
                *(uint2*)&Pls[w][l15 * LDK + ct * 16 + g * 4] = pw;
            }

            // ---- PV: O^T += V^T * P^T; l += 1 * P^T (ones-MFMA row-sum) ----
            const s16x8 pf0 = *(const s16x8*)&Pls[w][l15 * LDK + g * 8];
            const s16x8 pf1 = *(const s16x8*)&Pls[w][l15 * LDK + 32 + g * 8];
            *lsa = __builtin_amdgcn_mfma_f32_16x16x32_bf16(ones, pf0, *lsa, 0, 0, 0);
            *lsa = __builtin_amdgcn_mfma_f32_16x16x32_bf16(ones, pf1, *lsa, 0, 0, 0);
            #pragma unroll
            for (int nt = 0; nt < 4; ++nt) {
                const s16x8 bv0 = *(const s16x8*)&Vls[buf][(nt * 16 + l15) * LDK + g * 8];
                const s16x8 bv1 = *(const s16x8*)&Vls[buf][(nt * 16 + l15) * LDK + 32 + g * 8];
                Oacc[nt] = __builtin_amdgcn_mfma_f32_16x16x32_bf16(bv0, pf0, Oacc[nt], 0, 0, 0);
                Oacc[nt] = __builtin_amdgcn_mfma_f32_16x16x32_bf16(bv1, pf1, Oacc[nt], 0, 0, 0);
            }
        }
    }

    // ---- epilogue: l is complete per-query in every acc reg; store O ----
    const float invH = 1.0f / lsumHa[0];
    const float invL = 1.0f / lsumLa[0];

    #pragma unroll
    for (int half = 0; half < 2; ++half) {
        const f32x4* Oacc = (half == 0) ? OH : OL;
        const float  inv  = (half == 0) ? invH : invL;
        const int query   = ((half == 0) ? qH : qL) + l15;
        #pragma unroll
        for (int nt = 0; nt < 4; ++nt) {
            uint2 pk;
            pk.x = cvt_pk_bf16(Oacc[nt][0] * inv, Oacc[nt][1] * inv);
            pk.y = cvt_pk_bf16(Oacc[nt][2] * inv, Oacc[nt][3] * inv);
            *(uint2*)&O[(size_t)(b * 2048 + query) * 1024 + h * 64 + nt * 16 + g * 4] = pk;
        }
    }
}

// ---------------------------------------------------------------------------
// ws (ushort elems): xb 8M | Wqkvt 3M | Wot 1M | Qb/Kb/Vt 8M each | Ob 8M
// ---------------------------------------------------------------------------
extern "C" void kernel_launch(void* const* d_in, const int* in_sizes, int n_in,
                              void* d_out, int out_size, void* d_ws, size_t ws_size,
                              hipStream_t stream) {
    const float* x  = (const float*)d_in[0];
    const float* wq = (const float*)d_in[1];
    const float* bq = (const float*)d_in[2];
    const float* wk = (const float*)d_in[3];
    const float* bk = (const float*)d_in[4];
    const float* wv = (const float*)d_in[5];
    const float* bv = (const float*)d_in[6];
    const float* wo = (const float*)d_in[7];
    const float* bo = (const float*)d_in[8];
    float* out = (float*)d_out;

    const size_t hsz = (size_t)B_ * H_ * S_ * D_;        // 8388608
    unsigned short* xb    = (unsigned short*)d_ws;
    unsigned short* Wqkvt = xb + hsz;
    unsigned short* Wot   = Wqkvt + (size_t)3072 * 1024;
    unsigned short* Qb    = Wot + (size_t)1024 * 1024;
    unsigned short* Kb    = Qb + hsz;
    unsigned short* Vt    = Kb + hsz;
    unsigned short* Ob    = Vt + hsz;

    cast_x<<<4096, 256, 0, stream>>>(x, xb);
    transpose_w<<<dim3(16, 16, 49), 256, 0, stream>>>(wq, wk, wv, wo, Wqkvt, Wot);
    gemm_mfma<0><<<dim3(64, 12), 512, 0, stream>>>(
        xb, Wqkvt, bq, bk, bv, nullptr, Qb, Kb, Vt, nullptr);
    attn_mfma<<<dim3(8, H_, B_), 512, 0, stream>>>(Qb, Kb, Vt, Ob);
    gemm_mfma<1><<<dim3(64, 4), 512, 0, stream>>>(
        Ob, Wot, nullptr, nullptr, nullptr, bo, nullptr, nullptr, nullptr, out);
}

// Round 5
// 258.663 us; speedup vs baseline: 1.1942x; 1.0241x over previous
//
#include <hip/hip_runtime.h>
#include <math.h>

#define B_ 4
#define S_ 2048
#define E_ 1024
#define H_ 16
#define D_ 64

using f32x4 = __attribute__((ext_vector_type(4))) float;
using s16x8 = __attribute__((ext_vector_type(8))) short;

// fp32 -> bf16 bits, round-to-nearest-even
__device__ __forceinline__ unsigned short f2bf(float f) {
    unsigned int u = __float_as_uint(f);
    u = (u + 0x7FFFu + ((u >> 16) & 1u)) >> 16;
    return (unsigned short)u;
}

// pack two fp32 -> one u32 of 2x bf16 (RNE) in ONE VALU op (T12 primitive)
__device__ __forceinline__ unsigned int cvt_pk_bf16(float lo, float hi) {
    unsigned int r;
    asm("v_cvt_pk_bf16_f32 %0, %1, %2" : "=v"(r) : "v"(lo), "v"(hi));
    return r;
}

// raw 2^x (avoid libm range-fixup ops if builtin available)
__device__ __forceinline__ float fast_exp2(float x) {
#if __has_builtin(__builtin_amdgcn_exp2f)
    return __builtin_amdgcn_exp2f(x);
#else
    return exp2f(x);
#endif
}

// async global->LDS DMA, 16B per lane; LDS dest = wave-uniform base + lane*16
__device__ __forceinline__ void load_lds16(const void* g, void* l) {
    __builtin_amdgcn_global_load_lds(
        (const __attribute__((address_space(1))) void*)g,
        (__attribute__((address_space(3))) void*)l, 16, 0, 0);
}

#define WAITV(n) asm volatile("s_waitcnt vmcnt(" #n ")" ::: "memory")
#define WAITL(n) asm volatile("s_waitcnt lgkmcnt(" #n ")" ::: "memory")
#define SCHEDB __builtin_amdgcn_sched_barrier(0)

// Q pre-scale: 1/sqrt(D) * log2(e) -> softmax in base-2 (native v_exp_f32)
#define QSCALE 0.18033688011112042f

// ---------------------------------------------------------------------------
// x (fp32 [8192][1024]) -> bf16, same layout.
// ---------------------------------------------------------------------------
__global__ __launch_bounds__(256)
void cast_x(const float* __restrict__ in, unsigned short* __restrict__ out)
{
    const size_t idx = (size_t)blockIdx.x * 2048 + threadIdx.x * 8;
    const float4 v0 = *(const float4*)&in[idx];
    const float4 v1 = *(const float4*)&in[idx + 4];
    uint4 p;
    p.x = (unsigned)f2bf(v0.x) | ((unsigned)f2bf(v0.y) << 16);
    p.y = (unsigned)f2bf(v0.z) | ((unsigned)f2bf(v0.w) << 16);
    p.z = (unsigned)f2bf(v1.x) | ((unsigned)f2bf(v1.y) << 16);
    p.w = (unsigned)f2bf(v1.z) | ((unsigned)f2bf(v1.w) << 16);
    *(uint4*)&out[idx] = p;
}

// ---------------------------------------------------------------------------
// Weight transpose + bf16 cast (unchanged).
// ---------------------------------------------------------------------------
__global__ __launch_bounds__(256)
void transpose_w(const float* __restrict__ wq, const float* __restrict__ wk,
                 const float* __restrict__ wv, const float* __restrict__ wo,
                 unsigned short* __restrict__ Wqkvt, unsigned short* __restrict__ Wot)
{
    __shared__ float T[64][68];
    const int z = blockIdx.z;
    const float* in;
    unsigned short* out;
    int inStride, r0, c0;
    if (z < 48) {
        if (blockIdx.y != 0) return;
        const int t = z >> 4, h = z & 15;
        const float* W = (t == 0) ? wq : ((t == 1) ? wk : wv);
        in = W + (size_t)h * (E_ * D_);
        inStride = 64;
        out = Wqkvt + (size_t)(t * 1024 + h * 64) * 1024;
        r0 = blockIdx.x * 64; c0 = 0;
    } else {
        in = wo; inStride = 1024;
        out = Wot;
        r0 = blockIdx.x * 64; c0 = blockIdx.y * 64;
    }
    const int tid = threadIdx.x;
    #pragma unroll
    for (int i = 0; i < 4; ++i) {
        const int e = tid + i * 256;
        const int row = e >> 4, c4 = e & 15;
        const float4 v = *(const float4*)&in[(size_t)(r0 + row) * inStride + c0 + c4 * 4];
        T[row][c4 * 4 + 0] = v.x; T[row][c4 * 4 + 1] = v.y;
        T[row][c4 * 4 + 2] = v.z; T[row][c4 * 4 + 3] = v.w;
    }
    __syncthreads();
    #pragma unroll
    for (int i = 0; i < 2; ++i) {
        const int e = tid + i * 256;
        const int c = e >> 3, ch = e & 7;
        unsigned short h8[8];
        #pragma unroll
        for (int j = 0; j < 8; ++j) h8[j] = f2bf(T[ch * 8 + j][c]);
        uint4 p;
        p.x = (unsigned)h8[0] | ((unsigned)h8[1] << 16);
        p.y = (unsigned)h8[2] | ((unsigned)h8[3] << 16);
        p.z = (unsigned)h8[4] | ((unsigned)h8[5] << 16);
        p.w = (unsigned)h8[6] | ((unsigned)h8[7] << 16);
        *(uint4*)&out[(size_t)(c0 + c) * 1024 + r0 + ch * 8] = p;
    }
}

// ---------------------------------------------------------------------------
// bf16 MFMA GEMM v7 — fragment-register double-buffer pipeline.
//   R4 model: lockstep {reads -> barrier -> MFMA} serialized ~585-cyc LDS
//   bursts with ~512-cyc MFMA bursts (measured 3916 cyc/K-tile, MfmaUtil 26%).
//   v7 overlaps them: each wave holds TWO fragment sets (F0/F1).
//   Per K-tile t (buf = t%3, 3-buffer LDS ring, DMA lookahead 2):
//     issue F1 reads (ks=1, buf) ; stage tile t+2 (6 DMA)
//     lgkmcnt(8)  -> F0 ready, F1 still in flight under MFMA    [counted]
//     MFMA x16 (F0)
//     lgkmcnt(0)  -> all this tile's reads done (WAR license)
//     vmcnt(6)    -> tile t+1's DMA retired (t+2's 6 in flight)  [counted]
//     s_barrier   -> publish t+1  (ONE barrier per K-tile)
//     issue F0' reads (ks=0, tile t+1) ; lgkmcnt(8)
//     MFMA x16 (F1)
//   WAR safety: the pre-barrier lgkmcnt(0) guarantees every wave's reads of
//   buffer (t-1)%3 completed before any wave stages t+2 into it next iter.
//   Rule #18: every inline lgkmcnt is followed by sched_barrier(0).
//   Swizzle (verified conflict-free in R2-R4) unchanged.
// MODE 0: QKV — BM=128,BN=256, grid 64x12 = 768 (3 CU rounds).
// MODE 1: out — grid 64x4 = 256 (1 CU round).
// ---------------------------------------------------------------------------
template<int MODE>
__global__ __launch_bounds__(512, 2)
void gemm_mfma(const unsigned short* __restrict__ A,
               const unsigned short* __restrict__ Bt,
               const float* __restrict__ bq, const float* __restrict__ bk,
               const float* __restrict__ bv, const float* __restrict__ bo,
               unsigned short* __restrict__ Qb, unsigned short* __restrict__ Kb,
               unsigned short* __restrict__ Vt, float* __restrict__ Cout)
{
    __shared__ short As[3][128 * 64];
    __shared__ short Bs[3][256 * 64];

    const int tid  = threadIdx.x;
    const int w    = tid >> 6, lane = tid & 63;
    const int g    = lane >> 4, l15 = lane & 15;
    const int wm   = w >> 2, wn = w & 3;
    const int mbase = blockIdx.x * 128;
    const int nbase = blockIdx.y * 256;

    const int srow   = lane >> 3;                 // 0..7 row within unit
    const int schunk = (lane & 7) ^ srow;         // pre-swizzled source chunk
    const size_t aoff = (size_t)(mbase + srow) * 1024 + schunk * 8;
    const size_t boff = (size_t)(nbase + srow) * 1024 + schunk * 8;

    f32x4 acc[4][4];
    #pragma unroll
    for (int mt = 0; mt < 4; ++mt)
        #pragma unroll
        for (int nt = 0; nt < 4; ++nt)
            acc[mt][nt] = (f32x4){0.f, 0.f, 0.f, 0.f};

    // stage one full K-tile: A 2 units + B 4 units per wave = 6 DMAs
    auto STAGE = [&](int t, int buf) {
        #pragma unroll
        for (int i = 0; i < 2; ++i) {
            const int u = w * 2 + i;
            load_lds16(&A[aoff + (size_t)(u * 8) * 1024 + t * 64], &As[buf][u * 512]);
        }
        #pragma unroll
        for (int i = 0; i < 4; ++i) {
            const int u = w * 4 + i;
            load_lds16(&Bt[boff + (size_t)(u * 8) * 1024 + t * 64], &Bs[buf][u * 512]);
        }
    };

    const int pr  = l15 & 7;
    const int pc0 = (g ^ pr) * 8;                 // ks=0 swizzled chunk
    const int pc1 = ((4 + g) ^ pr) * 8;           // ks=1 swizzled chunk

    s16x8 a0[4], b0[4], a1[4], b1[4];
    auto LDF = [&](s16x8* af, s16x8* bf, int buf, int pc) {
        #pragma unroll
        for (int mt = 0; mt < 4; ++mt)
            af[mt] = *(const s16x8*)&As[buf][(wm * 64 + mt * 16 + l15) * 64 + pc];
        #pragma unroll
        for (int nt = 0; nt < 4; ++nt)
            bf[nt] = *(const s16x8*)&Bs[buf][(wn * 64 + nt * 16 + l15) * 64 + pc];
    };
    auto MFMA16 = [&](const s16x8* af, const s16x8* bf) {
        __builtin_amdgcn_s_setprio(1);
        #pragma unroll
        for (int mt = 0; mt < 4; ++mt)
            #pragma unroll
            for (int nt = 0; nt < 4; ++nt)
                acc[mt][nt] = __builtin_amdgcn_mfma_f32_16x16x32_bf16(
                    af[mt], bf[nt], acc[mt][nt], 0, 0, 0);
        __builtin_amdgcn_s_setprio(0);
    };

    // prologue: stage tiles 0,1; publish tile 0; prefetch its ks=0 frags
    STAGE(0, 0); STAGE(1, 1);
    WAITV(6);
    __builtin_amdgcn_s_barrier();
    LDF(a0, b0, 0, pc0);

    #pragma unroll 1
    for (int t = 0; t < 16; ++t) {
        const int buf = t % 3;
        LDF(a1, b1, buf, pc1);                    // ks=1 frags in flight
        if (t + 2 < 16) STAGE(t + 2, (t + 2) % 3);
        WAITL(8); SCHEDB;                         // F0 ready (F1 outstanding)
        MFMA16(a0, b0);
        WAITL(0); SCHEDB;                         // F1 done; WAR license
        if (t < 15) {
            if (t < 14) { WAITV(6); } else { WAITV(0); }
            __builtin_amdgcn_s_barrier();         // publish tile t+1
            LDF(a0, b0, (t + 1) % 3, pc0);        // next tile's ks=0 frags
            WAITL(8); SCHEDB;                     // (no-op; pins order)
        }
        MFMA16(a1, b1);
    }

    #pragma unroll
    for (int nt = 0; nt < 4; ++nt) {
        const int ncol = nbase + wn * 64 + nt * 16 + l15;
        if (MODE == 0) {
            const int tt = ncol >> 10;
            const int hh = (ncol >> 6) & 15;
            const int d  = ncol & 63;
            const float* bias = (tt == 0) ? bq : ((tt == 1) ? bk : bv);
            const float sc = (tt == 0) ? QSCALE : 1.0f;
            const float bval = bias[hh * 64 + d];
            #pragma unroll
            for (int mt = 0; mt < 4; ++mt)
                #pragma unroll
                for (int r = 0; r < 4; ++r) {
                    const int m = mbase + wm * 64 + mt * 16 + g * 4 + r;
                    const int b = m >> 11, s = m & 2047;
                    const unsigned short val = f2bf((acc[mt][nt][r] + bval) * sc);
                    if (tt == 2)
                        Vt[((size_t)(b * 16 + hh) * 64 + d) * 2048 + s] = val;
                    else {
                        unsigned short* Out = (tt == 0) ? Qb : Kb;
                        Out[((size_t)(b * 16 + hh) * 2048 + s) * 64 + d] = val;
                    }
                }
        } else {
            const float bval = bo[ncol];
            #pragma unroll
            for (int mt = 0; mt < 4; ++mt)
                #pragma unroll
                for (int r = 0; r < 4; ++r) {
                    const int m = mbase + wm * 64 + mt * 16 + g * 4 + r;
                    Cout[(size_t)m * 1024 + ncol] = acc[mt][nt][r] + bval;
                }
        }
    }
}

// ---------------------------------------------------------------------------
// MFMA flash attention v8 (unchanged from R4 — verified win: dropped off
// top-5). cvt_pk bf16 packing, ones-MFMA row-sum, raw exp2.
// ---------------------------------------------------------------------------
#define LDK 72
__global__ __launch_bounds__(512, 2)
void attn_mfma(const unsigned short* __restrict__ Qb,
               const unsigned short* __restrict__ Kb,
               const unsigned short* __restrict__ Vt,
               unsigned short* __restrict__ O)
{
    __shared__ short Kls[2][64 * LDK];
    __shared__ short Vls[2][64 * LDK];       // [d][key]
    __shared__ short Pls[8][16 * LDK];       // per-wave P [query][key]

    const int tid  = threadIdx.x;
    const int w    = tid >> 6;               // 0..7
    const int lane = tid & 63;
    const int g    = lane >> 4;
    const int l15  = lane & 15;
    const int j    = blockIdx.x;             // 0..7 (light tile index)
    const int j2   = 15 - j;                 // heavy tile index
    const int h    = blockIdx.y;
    const int b    = blockIdx.z;

    const size_t hb = (size_t)(b * 16 + h) * (2048 * 64);
    const int qH = j2 * 128 + w * 16;        // this wave's heavy query base
    const int qL = j * 128 + w * 16;         // this wave's light query base

    s16x8 aqH[2], aqL[2];
    {
        const int rh = qH + l15, rl = qL + l15;
        aqH[0] = *(const s16x8*)&Qb[hb + (size_t)rh * 64 + g * 8];
        aqH[1] = *(const s16x8*)&Qb[hb + (size_t)rh * 64 + 32 + g * 8];
        aqL[0] = *(const s16x8*)&Qb[hb + (size_t)rl * 64 + g * 8];
        aqL[1] = *(const s16x8*)&Qb[hb + (size_t)rl * 64 + 32 + g * 8];
    }

    // all-ones bf16 A-frag for the row-sum MFMA (bf16 1.0 = 0x3F80)
    const s16x8 ones = (s16x8){(short)0x3F80, (short)0x3F80, (short)0x3F80,
                               (short)0x3F80, (short)0x3F80, (short)0x3F80,
                               (short)0x3F80, (short)0x3F80};

    f32x4 lsumHa = (f32x4){0.f,0.f,0.f,0.f};
    f32x4 lsumLa = (f32x4){0.f,0.f,0.f,0.f};
    f32x4 OH[4], OL[4];                      // O^T: col query, rows d
    #pragma unroll
    for (int nt = 0; nt < 4; ++nt) { OH[nt] = (f32x4){0.f,0.f,0.f,0.f}; OL[nt] = (f32x4){0.f,0.f,0.f,0.f}; }

    const int stages      = 32 - 2 * j;
    const int lightStages = 2 * j + 2;

    const int srow = tid >> 3, spart = tid & 7;
    uint4 kreg = *(const uint4*)&Kb[hb + (size_t)srow * 64 + spart * 8];
    uint4 vreg = *(const uint4*)&Vt[hb + (size_t)srow * 2048 + spart * 8];

    for (int t = 0; t < stages; ++t) {
        const int t0  = t * 64;
        const int buf = t & 1;
        *(uint4*)&Kls[buf][srow * LDK + spart * 8] = kreg;
        *(uint4*)&Vls[buf][srow * LDK + spart * 8] = vreg;
        if (t + 1 < stages) {
            kreg = *(const uint4*)&Kb[hb + (size_t)(t0 + 64 + srow) * 64 + spart * 8];
            vreg = *(const uint4*)&Vt[hb + (size_t)srow * 2048 + t0 + 64 + spart * 8];
        }
        __syncthreads();

        #pragma unroll
        for (int half = 0; half < 2; ++half) {
            if (half == 1 && t >= lightStages) break;
            const s16x8* aq   = (half == 0) ? aqH : aqL;
            const int qbase   = (half == 0) ? qH : qL;
            f32x4* Oacc       = (half == 0) ? OH : OL;
            f32x4* lsa        = (half == 0) ? &lsumHa : &lsumLa;

            // ---- S^T = K * Q^T : Sf[ct][r] = S[query=l15][key=t0+ct*16+g*4+r]
            f32x4 Sf[4];
            #pragma unroll
            for (int ct = 0; ct < 4; ++ct) {
                f32x4 acc = (f32x4){0.f, 0.f, 0.f, 0.f};
                const s16x8 bk0 = *(const s16x8*)&Kls[buf][(ct * 16 + l15) * LDK + g * 8];
                const s16x8 bk1 = *(const s16x8*)&Kls[buf][(ct * 16 + l15) * LDK + 32 + g * 8];
                acc = __builtin_amdgcn_mfma_f32_16x16x32_bf16(bk0, aq[0], acc, 0, 0, 0);
                acc = __builtin_amdgcn_mfma_f32_16x16x32_bf16(bk1, aq[1], acc, 0, 0, 0);
                Sf[ct] = acc;
            }

            // ---- causal mask (diagonal tiles only) ----
            if (t0 + 63 > qbase) {
                const int query = qbase + l15;
                #pragma unroll
                for (int ct = 0; ct < 4; ++ct) {
                    const int kbase = t0 + ct * 16 + g * 4;
                    #pragma unroll
                    for (int r = 0; r < 4; ++r)
                        if (kbase + r > query) Sf[ct][r] = -1e30f;
                }
            }

            // ---- p = exp2(s) ----
            #pragma unroll
            for (int ct = 0; ct < 4; ++ct)
                #pragma unroll
                for (int r = 0; r < 4; ++r) Sf[ct][r] = fast_exp2(Sf[ct][r]);

            // ---- write P[query][key]: cvt_pk (1 VALU per pair) -> b64 ----
            #pragma unroll
            for (int ct = 0; ct < 4; ++ct) {
                uint2 pw;
                pw.x = cvt_pk_bf16(Sf[ct][0], Sf[ct][1]);
                pw.y = cvt_pk_bf16(Sf[ct][2], Sf[ct][3]);
                *(uint2*)&Pls[w][l15 * LDK + ct * 16 + g * 4] = pw;
            }

            // ---- PV: O^T += V^T * P^T; l += 1 * P^T (ones-MFMA row-sum) ----
            const s16x8 pf0 = *(const s16x8*)&Pls[w][l15 * LDK + g * 8];
            const s16x8 pf1 = *(const s16x8*)&Pls[w][l15 * LDK + 32 + g * 8];
            *lsa = __builtin_amdgcn_mfma_f32_16x16x32_bf16(ones, pf0, *lsa, 0, 0, 0);
            *lsa = __builtin_amdgcn_mfma_f32_16x16x32_bf16(ones, pf1, *lsa, 0, 0, 0);
            #pragma unroll
            for (int nt = 0; nt < 4; ++nt) {
                const s16x8 bv0 = *(const s16x8*)&Vls[buf][(nt * 16 + l15) * LDK + g * 8];
                const s16x8 bv1 = *(const s16x8*)&Vls[buf][(nt * 16 + l15) * LDK + 32 + g * 8];
                Oacc[nt] = __builtin_amdgcn_mfma_f32_16x16x32_bf16(bv0, pf0, Oacc[nt], 0, 0, 0);
                Oacc[nt] = __builtin_amdgcn_mfma_f32_16x16x32_bf16(bv1, pf1, Oacc[nt], 0, 0, 0);
            }
        }
    }

    // ---- epilogue: l is complete per-query in every acc reg; store O ----
    const float invH = 1.0f / lsumHa[0];
    const float invL = 1.0f / lsumLa[0];

    #pragma unroll
    for (int half = 0; half < 2; ++half) {
        const f32x4* Oacc = (half == 0) ? OH : OL;
        const float  inv  = (half == 0) ? invH : invL;
        const int query   = ((half == 0) ? qH : qL) + l15;
        #pragma unroll
        for (int nt = 0; nt < 4; ++nt) {
            uint2 pk;
            pk.x = cvt_pk_bf16(Oacc[nt][0] * inv, Oacc[nt][1] * inv);
            pk.y = cvt_pk_bf16(Oacc[nt][2] * inv, Oacc[nt][3] * inv);
            *(uint2*)&O[(size_t)(b * 2048 + query) * 1024 + h * 64 + nt * 16 + g * 4] = pk;
        }
    }
}

// ---------------------------------------------------------------------------
// ws (ushort elems): xb 8M | Wqkvt 3M | Wot 1M | Qb/Kb/Vt 8M each | Ob 8M
// ---------------------------------------------------------------------------
extern "C" void kernel_launch(void* const* d_in, const int* in_sizes, int n_in,
                              void* d_out, int out_size, void* d_ws, size_t ws_size,
                              hipStream_t stream) {
    const float* x  = (const float*)d_in[0];
    const float* wq = (const float*)d_in[1];
    const float* bq = (const float*)d_in[2];
    const float* wk = (const float*)d_in[3];
    const float* bk = (const float*)d_in[4];
    const float* wv = (const float*)d_in[5];
    const float* bv = (const float*)d_in[6];
    const float* wo = (const float*)d_in[7];
    const float* bo = (const float*)d_in[8];
    float* out = (float*)d_out;

    const size_t hsz = (size_t)B_ * H_ * S_ * D_;        // 8388608
    unsigned short* xb    = (unsigned short*)d_ws;
    unsigned short* Wqkvt = xb + hsz;
    unsigned short* Wot   = Wqkvt + (size_t)3072 * 1024;
    unsigned short* Qb    = Wot + (size_t)1024 * 1024;
    unsigned short* Kb    = Qb + hsz;
    unsigned short* Vt    = Kb + hsz;
    unsigned short* Ob    = Vt + hsz;

    cast_x<<<4096, 256, 0, stream>>>(x, xb);
    transpose_w<<<dim3(16, 16, 49), 256, 0, stream>>>(wq, wk, wv, wo, Wqkvt, Wot);
    gemm_mfma<0><<<dim3(64, 12), 512, 0, stream>>>(
        xb, Wqkvt, bq, bk, bv, nullptr, Qb, Kb, Vt, nullptr);
    attn_mfma<<<dim3(8, H_, B_), 512, 0, stream>>>(Qb, Kb, Vt, Ob);
    gemm_mfma<1><<<dim3(64, 4), 512, 0, stream>>>(
        Ob, Wot, nullptr, nullptr, nullptr, bo, nullptr, nullptr, nullptr, out);
}